// Round 7
// baseline (938.215 us; speedup 1.0000x reference)
//
#include <hip/hip_runtime.h>
#include <hip/hip_bf16.h>
#include <hip/hip_cooperative_groups.h>
#include <string.h>

namespace cg = cooperative_groups;

#define NN   4096
#define NE   32768
#define NB   32
#define BKT  64   // per-src edge bucket capacity (deg ~ Poisson(8); P(>64) ~ 1e-30)
#define MSG_CHUNK 8

typedef __attribute__((ext_vector_type(8))) short short8;
typedef __attribute__((ext_vector_type(4))) float f4;

__device__ __forceinline__ float sigf(float x) { return 1.0f / (1.0f + __expf(-x)); }
__device__ __forceinline__ short f2bf(float f) {
    __hip_bfloat16 h = __float2bfloat16(f);
    short s;
    memcpy(&s, &h, sizeof(short));
    return s;
}

// ---------------- k_setup: zero/init + W2->W2F fragment repack ----------------
// blocks 0..31: zero counters + agg, init batch ranges
// blocks 32..223: enn_W2[l][g][k][o] -> W2F fragment-packed bf16 (MFMA-ready)
__global__ __launch_bounds__(256) void k_setup(const float* __restrict__ enn_W2,
        __hip_bfloat16* __restrict__ W2F, float* __restrict__ agg,
        int* cnt_src, int* cnt_dst, int* bstart, int* bend) {
    int bid = blockIdx.x, t = threadIdx.x;
    if (bid < 32) {
        int i = bid * 256 + t;
        if (i < NN) cnt_src[i] = 0;
        else cnt_dst[i - NN] = 0;
        if (i < NB) { bstart[i] = 0x7FFFFFFF; bend[i] = 0; }
        for (int z = i; z < NN * 64; z += 8192) agg[z] = 0.f;
    } else {
        __shared__ __hip_bfloat16 tile[4096];
        size_t base = (size_t)(bid - 32) * 4096;
        for (int i = t; i < 4096; i += 256) {
            int k = i >> 6, o = i & 63;
            int pos = ((o >> 4) << 10) | ((k >> 5) << 9) | (((k >> 3) & 3) << 7)
                    | ((o & 15) << 3) | (k & 7);
            tile[pos] = __float2bfloat16(enn_W2[base + i]);
        }
        __syncthreads();
        for (int i = t; i < 4096; i += 256) W2F[base + i] = tile[i];
    }
}

// ---------------- k_bucket: bucket CSR fill + batch ranges + S2S weight transpose ---
__global__ __launch_bounds__(256) void k_bucket(const int* __restrict__ eidx,
        const float* __restrict__ ea, const int* __restrict__ bm,
        const float* __restrict__ Wih, const float* __restrict__ Whh,
        float* __restrict__ WihT, float* __restrict__ WhhT,
        int* cnt_src, int* cnt_dst, int* csr_dst, float* csr_ea,
        int* bstart, int* bend) {
    int t = threadIdx.x;
    if (blockIdx.x >= 128) {
        int c0 = (blockIdx.x - 128) * 8;
        for (int i = t; i < 1024; i += 256) {
            int c = c0 + (i >> 7), j = i & 127;
            WihT[(size_t)c * 128 + j] = Wih[(size_t)j * 256 + c];
        }
        for (int i = t; i < 512; i += 256) {
            int c = c0 + (i >> 6), j = i & 63;
            WhhT[(size_t)c * 64 + j] = Whh[(size_t)j * 256 + c];
        }
        return;
    }
    int e = blockIdx.x * 256 + t;
    if (e < NE) {
        int s = eidx[e];
        int d = eidx[NE + e];
        int slot = atomicAdd(&cnt_src[s], 1);
        if (slot < BKT) {
            csr_dst[s * BKT + slot] = d;
            csr_ea[s * BKT + slot] = ea[e];
        }
        atomicAdd(&cnt_dst[d], 1);
    }
    if (e < NN) {
        int b = bm[e];
        atomicMin(&bstart[b], e);
        atomicMax(&bend[b], e + 1);
    }
}

// ---------------- k_mega: pre-MLP + 3x(P-MFMA + scatter + gridsync + GRU) ----------
// Cooperative kernel, grid 512 = exactly 2 blocks/CU (LDS 76 KB). Block owns 8 nodes
// for the WHOLE network: out lives in LDS outs[] across all 3 layers (no global
// round-trips). agg is the only cross-block flow: scatter atomicAdd -> grid.sync ->
// GRU consumes via atomicExch(...,0) (coherent read+zero, no stale-L1 risk) ->
// grid.sync -> next layer. All FMA chains are operand-identical to the proven
// k_setup/k_fused/k_gru code.
__global__ __launch_bounds__(256, 2) void k_mega(const float* __restrict__ x,
        const float* __restrict__ mW0, const float* __restrict__ mb0,
        const float* __restrict__ mW1, const float* __restrict__ mb1,
        const float* __restrict__ mW2, const float* __restrict__ mb2,
        const __hip_bfloat16* __restrict__ W2F, const float* __restrict__ enn_b2,
        const float* __restrict__ enn_W1, const float* __restrict__ enn_b1,
        const float* __restrict__ rootW, const float* __restrict__ convb,
        const float* __restrict__ gWih, const float* __restrict__ gWhh,
        const float* __restrict__ gbih, const float* __restrict__ gbhh,
        const int* __restrict__ cnt_src, const int* __restrict__ cnt_dst,
        const int* __restrict__ csr_dst, const float* __restrict__ csr_ea,
        float* __restrict__ agg, float* __restrict__ outG) {
    cg::grid_group grid = cg::this_grid();
    __shared__ float outs[8][68];                     // fp32 node state (padded)
    __shared__ __hip_bfloat16 Pt[8 * 4096];           // 64 KB swizzled P tile
    __shared__ float wlds[4][MSG_CHUNK][64];          // 8 KB We1 buffers (wave-private)
    int t = threadIdx.x, wave = t >> 6, lane = t & 63;
    int laneM = lane & 15, quad = lane >> 4;
    int n0 = blockIdx.x * 8;
    int j = lane;
    float* xs  = (float*)Pt;                          // pre-MLP x staging (alias)
    float* haL = &wlds[0][0][0];                      // pre-MLP/GRU temp rows (alias)
    float* hbL = haL + 512;
    // ---- pre-MLP for the block's 8 nodes (same FMA order as old k_setup) ----
    for (int i = t; i < 1024; i += 256) xs[i] = x[(size_t)n0 * 128 + i];
    __syncthreads();
    for (int u = 0; u < 2; ++u) {
        int nl = wave * 2 + u;
        const float* xr = xs + nl * 128;
        float s = mb0[j];
        #pragma unroll 8
        for (int k = 0; k < 128; ++k) s = fmaf(xr[k], mW0[k * 64 + j], s);
        haL[nl * 64 + j] = fmaxf(s, 0.f);
        s = mb1[j];
        #pragma unroll 8
        for (int k = 0; k < 64; ++k) s = fmaf(haL[nl * 64 + k], mW1[k * 64 + j], s);
        hbL[nl * 64 + j] = fmaxf(s, 0.f);
        s = mb2[j];
        #pragma unroll 8
        for (int k = 0; k < 64; ++k) s = fmaf(hbL[nl * 64 + k], mW2[k * 64 + j], s);
        outs[nl][j] = fmaxf(s, 0.f);
    }
    __syncthreads();
    for (int l = 0; l < 3; ++l) {
        const __hip_bfloat16* W2F_l = W2F + (size_t)l * 64 * 4096;
        const float* b2l = enn_b2 + (size_t)l * 4096;
        const float* W1l = enn_W1 + l * 64;
        const float* b1l = enn_b1 + l * 64;
        // A fragments (rows = 8 nodes, rows 8..15 duplicated; K = 64)
        short8 a0, a1;
        {
            const float* ar = &outs[laneM & 7][quad * 8];
            #pragma unroll
            for (int q = 0; q < 8; ++q) a0[q] = f2bf(ar[q]);
            const float* ar2 = &outs[laneM & 7][32 + quad * 8];
            #pragma unroll
            for (int q = 0; q < 8; ++q) a1[q] = f2bf(ar2[q]);
        }
        // BT (same summation order as proven kernel)
        float btr[2] = {0.f, 0.f};
        for (int k = 0; k < 64; ++k) {
            float bv = b2l[k * 64 + lane];
            #pragma unroll
            for (int u = 0; u < 2; ++u) btr[u] = fmaf(outs[wave * 2 + u][k], bv, btr[u]);
        }
        // Phase 1: wave w owns g in [16w, 16w+16), as 8 adjacent pairs
        #pragma unroll 2
        for (int gp = 0; gp < 8; ++gp) {
            int gA = wave * 16 + gp * 2;               // even g
            const __hip_bfloat16* BgA = W2F_l + (size_t)gA * 4096;
            const __hip_bfloat16* BgB = BgA + 4096;
            int c = gA >> 3;                           // g octet (0..7)
            int p = (gA >> 1) & 3;                     // pair-dword index in octet
            char* wb = (char*)Pt + (quad << 15) + (c << 10) + (laneM << 4)
                     + (((p ^ quad) & 3) << 2);
            #pragma unroll
            for (int sub = 0; sub < 4; ++sub) {
                short8 bA0 = *(const short8*)(BgA + sub * 1024 + lane * 8);
                short8 bA1 = *(const short8*)(BgA + sub * 1024 + 512 + lane * 8);
                short8 bB0 = *(const short8*)(BgB + sub * 1024 + lane * 8);
                short8 bB1 = *(const short8*)(BgB + sub * 1024 + 512 + lane * 8);
                f4 accA = {0.f, 0.f, 0.f, 0.f}, accB = {0.f, 0.f, 0.f, 0.f};
                accA = __builtin_amdgcn_mfma_f32_16x16x32_bf16(a0, bA0, accA, 0, 0, 0);
                accA = __builtin_amdgcn_mfma_f32_16x16x32_bf16(a1, bA1, accA, 0, 0, 0);
                accB = __builtin_amdgcn_mfma_f32_16x16x32_bf16(a0, bB0, accB, 0, 0, 0);
                accB = __builtin_amdgcn_mfma_f32_16x16x32_bf16(a1, bB1, accB, 0, 0, 0);
                if (quad < 2) {                        // nodes = quad*4+r in 0..7
                    char* wbs = wb + (sub << 8);       // o += 16 -> 256 B
                    #pragma unroll
                    for (int r = 0; r < 4; ++r) {
                        unsigned pk = (unsigned)(unsigned short)f2bf(accA[r])
                                    | ((unsigned)(unsigned short)f2bf(accB[r]) << 16);
                        *(unsigned*)(wbs + (r << 13)) = pk;    // node stride 8192 B
                    }
                }
            }
        }
        __syncthreads();
        // Phase 2: full-g message scatter, 2 srcs per wave, one atomic per edge
        float w1v = W1l[lane], b1v = b1l[lane];
        for (int u = 0; u < 2; ++u) {
            int nloc = wave * 2 + u;
            int n = n0 + nloc;
            int deg = cnt_src[n];
            if (deg > BKT) deg = BKT;
            if (deg <= 0) continue;
            int wq = nloc >> 2;                        // writer quad (0 or 1)
            float preg[64];                            // P[n, g 0..63, o=lane]
            const char* Pn = (const char*)Pt + (nloc << 13);
            #pragma unroll
            for (int c = 0; c < 8; ++c) {
                uint4 vv = *(const uint4*)(Pn + (c << 10) + (lane << 4));
                unsigned d0 = vv.x, d1 = vv.y, d2 = vv.z, d3 = vv.w;
                if (wq & 1) { unsigned tt = d0; d0 = d1; d1 = tt; tt = d2; d2 = d3; d3 = tt; }
                union { unsigned u2; float f; } cv;
                cv.u2 = d0 << 16;          preg[c * 8 + 0] = cv.f;
                cv.u2 = d0 & 0xFFFF0000u;  preg[c * 8 + 1] = cv.f;
                cv.u2 = d1 << 16;          preg[c * 8 + 2] = cv.f;
                cv.u2 = d1 & 0xFFFF0000u;  preg[c * 8 + 3] = cv.f;
                cv.u2 = d2 << 16;          preg[c * 8 + 4] = cv.f;
                cv.u2 = d2 & 0xFFFF0000u;  preg[c * 8 + 5] = cv.f;
                cv.u2 = d3 << 16;          preg[c * 8 + 6] = cv.f;
                cv.u2 = d3 & 0xFFFF0000u;  preg[c * 8 + 7] = cv.f;
            }
            float bt = btr[u];
            const int* bdst = csr_dst + n * BKT;
            const float* bea = csr_ea + n * BKT;
            for (int c0 = 0; c0 < deg; c0 += MSG_CHUNK) {
                int cc = deg - c0;
                if (cc > MSG_CHUNK) cc = MSG_CHUNK;
                int dl = 0; float el = 0.f;
                if (lane < cc) { dl = bdst[c0 + lane]; el = bea[c0 + lane]; }
                for (int si = 0; si < cc; ++si) {
                    float eav = __shfl(el, si, 64);
                    wlds[wave][si][lane] = fmaxf(fmaf(eav, w1v, b1v), 0.f);
                }
                for (int i = 0; i < cc; ++i) {
                    int dst = __shfl(dl, i, 64);
                    const float* wr = wlds[wave][i];
                    float acc0 = bt, acc1 = 0.f, acc2 = 0.f, acc3 = 0.f;
                    #pragma unroll
                    for (int g = 0; g < 64; g += 16) {
                        float4 w0 = *(const float4*)(wr + g);
                        float4 w1 = *(const float4*)(wr + g + 4);
                        float4 w2 = *(const float4*)(wr + g + 8);
                        float4 w3 = *(const float4*)(wr + g + 12);
                        acc0 = fmaf(w0.x, preg[g], acc0);
                        acc0 = fmaf(w0.y, preg[g + 1], acc0);
                        acc0 = fmaf(w0.z, preg[g + 2], acc0);
                        acc0 = fmaf(w0.w, preg[g + 3], acc0);
                        acc1 = fmaf(w1.x, preg[g + 4], acc1);
                        acc1 = fmaf(w1.y, preg[g + 5], acc1);
                        acc1 = fmaf(w1.z, preg[g + 6], acc1);
                        acc1 = fmaf(w1.w, preg[g + 7], acc1);
                        acc2 = fmaf(w2.x, preg[g + 8], acc2);
                        acc2 = fmaf(w2.y, preg[g + 9], acc2);
                        acc2 = fmaf(w2.z, preg[g + 10], acc2);
                        acc2 = fmaf(w2.w, preg[g + 11], acc2);
                        acc3 = fmaf(w3.x, preg[g + 12], acc3);
                        acc3 = fmaf(w3.y, preg[g + 13], acc3);
                        acc3 = fmaf(w3.z, preg[g + 14], acc3);
                        acc3 = fmaf(w3.w, preg[g + 15], acc3);
                    }
                    float acc = (acc0 + acc1) + (acc2 + acc3);
                    atomicAdd(&agg[(size_t)dst * 64 + lane], acc);
                }
            }
        }
        __threadfence();
        grid.sync();                                   // all scatter atomics landed
        // ---- GRU for own 8 nodes (same FMA order as old k_gru) ----
        const float* rootWl = rootW + (size_t)l * 4096;
        const float* convbl = convb + l * 64;
        const float* Wihl = gWih + (size_t)l * 64 * 192;
        const float* Whhl = gWhh + (size_t)l * 64 * 192;
        const float* bihl = gbih + l * 192;
        const float* bhhl = gbhh + l * 192;
        float* scL = haL;                              // reuse wlds (scatter done)
        for (int u = 0; u < 2; ++u) {
            int nl = wave * 2 + u;
            int n = n0 + nl;
            int dg = cnt_dst[n];
            float invd = 1.0f / (float)(dg > 0 ? dg : 1);
            float av = atomicExch(&agg[(size_t)n * 64 + j], 0.f);  // coherent read+zero
            float s = av * invd + convbl[j];
            #pragma unroll 8
            for (int k = 0; k < 64; ++k) s = fmaf(outs[nl][k], rootWl[k * 64 + j], s);
            scL[nl * 64 + j] = fmaxf(s, 0.f);
        }
        __syncthreads();
        float o_new[2];
        for (int u = 0; u < 2; ++u) {
            int nl = wave * 2 + u;
            float hj = outs[nl][j];
            float gir = bihl[j], giz = bihl[64 + j], gin = bihl[128 + j];
            float ghr = bhhl[j], ghz = bhhl[64 + j], ghn = bhhl[128 + j];
            #pragma unroll 4
            for (int k = 0; k < 64; ++k) {
                float c = scL[nl * 64 + k], h = outs[nl][k];
                gir = fmaf(c, Wihl[k * 192 + j], gir);
                giz = fmaf(c, Wihl[k * 192 + 64 + j], giz);
                gin = fmaf(c, Wihl[k * 192 + 128 + j], gin);
                ghr = fmaf(h, Whhl[k * 192 + j], ghr);
                ghz = fmaf(h, Whhl[k * 192 + 64 + j], ghz);
                ghn = fmaf(h, Whhl[k * 192 + 128 + j], ghn);
            }
            float r = sigf(gir + ghr);
            float z = sigf(giz + ghz);
            float nn2 = tanhf(gin + r * ghn);
            o_new[u] = (1.f - z) * nn2 + z * hj;
        }
        __syncthreads();
        for (int u = 0; u < 2; ++u) outs[wave * 2 + u][j] = o_new[u];
        __threadfence();
        grid.sync();                                   // agg zeroed + outs updated
    }
    for (int i = t; i < 512; i += 256)
        outG[(size_t)n0 * 64 + i] = outs[i >> 6][i & 63];
}

// ---------------- Set2Set (3 steps) + post-MLP: burst-latency version ---------------
__global__ __launch_bounds__(256, 1) void k_s2s_post(const float* __restrict__ out,
        const int* __restrict__ bstart, const int* __restrict__ bend,
        const float* __restrict__ WihT, const float* __restrict__ WhhT,
        const float* __restrict__ bih, const float* __restrict__ bhh,
        const float* __restrict__ pW0, const float* __restrict__ pb0,
        const float* __restrict__ pW1, const float* __restrict__ pb1,
        const float* __restrict__ pW2, const float* __restrict__ pb2,
        const float* __restrict__ pW3, const float* __restrict__ pb3,
        float* __restrict__ y) {
    __shared__ float cacheT[64 * 193];     // transposed node tile (49.4 KB)
    __shared__ float wpost[16448];         // pW0|pW1|pW2|pW3 (64.3 KB)
    __shared__ float qs[128];              // [0:64]=q(hh), [64:128]=r_read
    __shared__ float hh_l[64];
    __shared__ float gates_l[256];
    __shared__ float ebuf[1024];
    __shared__ float redw[4], redw2[4];
    __shared__ float redbuf[4][64];
    __shared__ float tmp64[64];
    int t = threadIdx.x, wave = t >> 6, lane = t & 63;
    int b = blockIdx.x;
    int s0 = bstart[b], e0 = bend[b];
    int cnt = e0 - s0;
    if (cnt < 0) cnt = 0;
    if (cnt > 1024) cnt = 1024;
    int ccnt = cnt < 192 ? cnt : 192;
    // ---- burst 1: node tile (<=192 rows -> <=3072 float4, 12 guarded/thread) ----
    int nf4 = ccnt * 16;
    const float4* out4 = (const float4*)(out + (size_t)s0 * 64);
    float4 stg[12];
    #pragma unroll
    for (int i = 0; i < 12; ++i) {
        int v = t + i * 256;
        if (v < nf4) stg[i] = out4[v];
    }
    #pragma unroll
    for (int i = 0; i < 12; ++i) {
        int v = t + i * 256;
        if (v < nf4) {
            int row = v >> 4, dq = v & 15;
            cacheT[(dq * 4 + 0) * 193 + row] = stg[i].x;
            cacheT[(dq * 4 + 1) * 193 + row] = stg[i].y;
            cacheT[(dq * 4 + 2) * 193 + row] = stg[i].z;
            cacheT[(dq * 4 + 3) * 193 + row] = stg[i].w;
        }
    }
    // ---- burst 2: post-MLP weights -> LDS (4112 float4 total) ----
    {
        float4* wp4 = (float4*)wpost;
        #pragma unroll
        for (int i = 0; i < 8; ++i) {
            int v = t + i * 256;
            wp4[v] = ((const float4*)pW0)[v];
        }
        #pragma unroll
        for (int i = 0; i < 4; ++i) {
            int v = t + i * 256;
            wp4[2048 + v] = ((const float4*)pW1)[v];
        }
        #pragma unroll
        for (int i = 0; i < 4; ++i) {
            int v = t + i * 256;
            wp4[3072 + v] = ((const float4*)pW2)[v];
        }
        if (t < 16) wp4[4096 + t] = ((const float4*)pW3)[t];
    }
    const float4* wihT4 = (const float4*)(WihT + (size_t)t * 128);
    const float4* whhT4 = (const float4*)(WhhT + (size_t)t * 64);
    float bsum = bih[t] + bhh[t];
    float ccr = 0.f;
    if (t < 128) qs[t] = 0.f;
    if (t < 64) hh_l[t] = 0.f;
    __syncthreads();
    const float4* qs4 = (const float4*)qs;
    const float4* hh4 = (const float4*)hh_l;
    for (int step = 0; step < 3; ++step) {
        float g0 = bsum, g1 = 0.f, g2 = 0.f, g3 = 0.f;
        #pragma unroll
        for (int jq = 0; jq < 32; ++jq) {
            float4 w = wihT4[jq];
            float4 v = qs4[jq];
            g0 = fmaf(v.x, w.x, g0);
            g1 = fmaf(v.y, w.y, g1);
            g2 = fmaf(v.z, w.z, g2);
            g3 = fmaf(v.w, w.w, g3);
        }
        #pragma unroll
        for (int jq = 0; jq < 16; ++jq) {
            float4 w = whhT4[jq];
            float4 v = hh4[jq];
            g0 = fmaf(v.x, w.x, g0);
            g1 = fmaf(v.y, w.y, g1);
            g2 = fmaf(v.z, w.z, g2);
            g3 = fmaf(v.w, w.w, g3);
        }
        gates_l[t] = (g0 + g1) + (g2 + g3);
        __syncthreads();                                     // B1: gates ready
        if (t < 64) {
            float cn = sigf(gates_l[64 + t]) * ccr
                     + sigf(gates_l[t]) * tanhf(gates_l[128 + t]);
            ccr = cn;
            hh_l[t] = sigf(gates_l[192 + t]) * tanhf(cn);
        }
        __syncthreads();                                     // B2: hh ready
        for (int idx = t; idx < cnt; idx += 256) {
            float s0a = 0.f, s1a = 0.f, s2a = 0.f, s3a = 0.f;
            if (idx < 192) {
                #pragma unroll
                for (int dq = 0; dq < 16; ++dq) {
                    float4 h = hh4[dq];
                    s0a = fmaf(cacheT[(dq * 4 + 0) * 193 + idx], h.x, s0a);
                    s1a = fmaf(cacheT[(dq * 4 + 1) * 193 + idx], h.y, s1a);
                    s2a = fmaf(cacheT[(dq * 4 + 2) * 193 + idx], h.z, s2a);
                    s3a = fmaf(cacheT[(dq * 4 + 3) * 193 + idx], h.w, s3a);
                }
            } else {
                const float* row = out + (size_t)(s0 + idx) * 64;
                #pragma unroll
                for (int dq = 0; dq < 16; ++dq) {
                    float4 h = hh4[dq];
                    s0a = fmaf(row[dq * 4 + 0], h.x, s0a);
                    s1a = fmaf(row[dq * 4 + 1], h.y, s1a);
                    s2a = fmaf(row[dq * 4 + 2], h.z, s2a);
                    s3a = fmaf(row[dq * 4 + 3], h.w, s3a);
                }
            }
            ebuf[idx] = (s0a + s1a) + (s2a + s3a);
        }
        __syncthreads();                                     // B3: e ready
        float lm = -3.0e38f;
        for (int idx = t; idx < cnt; idx += 256) lm = fmaxf(lm, ebuf[idx]);
        #pragma unroll
        for (int off = 32; off > 0; off >>= 1) lm = fmaxf(lm, __shfl_xor(lm, off, 64));
        if (lane == 0) redw[wave] = lm;
        __syncthreads();                                     // B4: wave maxes
        float m = fmaxf(fmaxf(redw[0], redw[1]), fmaxf(redw[2], redw[3]));
        float ls = 0.f;
        for (int idx = t; idx < cnt; idx += 256) {
            float a = __expf(ebuf[idx] - m);
            ebuf[idx] = a;
            ls += a;
        }
        #pragma unroll
        for (int off = 32; off > 0; off >>= 1) ls += __shfl_xor(ls, off, 64);
        if (lane == 0) redw2[wave] = ls;
        __syncthreads();                                     // B5: a's + wave sums
        float ssum = (redw2[0] + redw2[1]) + (redw2[2] + redw2[3]);
        float inv = (cnt > 0) ? 1.f / ssum : 0.f;
        float r0 = 0.f;
        for (int row = wave; row < ccnt; row += 4)
            r0 = fmaf(ebuf[row], cacheT[lane * 193 + row], r0);
        for (int row = 192 + wave; row < cnt; row += 4)
            r0 = fmaf(ebuf[row], out[(size_t)(s0 + row) * 64 + lane], r0);
        redbuf[wave][lane] = r0;
        __syncthreads();                                     // B6: wave partials
        if (t < 64) {
            float s = ((redbuf[0][t] + redbuf[1][t]) + (redbuf[2][t] + redbuf[3][t]));
            qs[64 + t] = s * inv;
            qs[t] = hh_l[t];
        }
        __syncthreads();                                     // B7: qs ready
    }
    if (t < 64) {
        float s = pb0[t];
        #pragma unroll 4
        for (int k = 0; k < 128; ++k) s = fmaf(qs[k], wpost[k * 64 + t], s);
        tmp64[t] = fmaxf(s, 0.f);
    }
    __syncthreads();
    float h1v = 0.f;
    if (t < 64) {
        float s = pb1[t];
        #pragma unroll 4
        for (int k = 0; k < 64; ++k) s = fmaf(tmp64[k], wpost[8192 + k * 64 + t], s);
        h1v = fmaxf(s, 0.f);
    }
    __syncthreads();
    if (t < 64) tmp64[t] = h1v;
    __syncthreads();
    if (t < 64) {
        float s = pb2[t];
        #pragma unroll 4
        for (int k = 0; k < 64; ++k) s = fmaf(tmp64[k], wpost[12288 + k * 64 + t], s);
        gates_l[t] = fmaxf(s, 0.f) * wpost[16384 + t];
    }
    __syncthreads();
    if (t == 0) {
        float yy = pb3[0];
        for (int k = 0; k < 64; ++k) yy += gates_l[k];
        y[b] = yy;
    }
}

// ---------------- host ----------------

extern "C" void kernel_launch(void* const* d_in, const int* in_sizes, int n_in,
                              void* d_out, int out_size, void* d_ws, size_t ws_size,
                              hipStream_t stream) {
    const float* x         = (const float*)d_in[0];
    const float* edge_attr = (const float*)d_in[1];
    const int*   edge_idx  = (const int*)d_in[2];
    const int*   batch_map = (const int*)d_in[3];
    const float* pre_W0 = (const float*)d_in[4];
    const float* pre_b0 = (const float*)d_in[5];
    const float* pre_W1 = (const float*)d_in[6];
    const float* pre_b1 = (const float*)d_in[7];
    const float* pre_W2 = (const float*)d_in[8];
    const float* pre_b2 = (const float*)d_in[9];
    const float* enn_W1 = (const float*)d_in[10];
    const float* enn_b1 = (const float*)d_in[11];
    const float* enn_W2 = (const float*)d_in[12];
    const float* enn_b2 = (const float*)d_in[13];
    const float* root_W = (const float*)d_in[14];
    const float* conv_b = (const float*)d_in[15];
    const float* gru_Wih = (const float*)d_in[16];
    const float* gru_Whh = (const float*)d_in[17];
    const float* gru_bih = (const float*)d_in[18];
    const float* gru_bhh = (const float*)d_in[19];
    const float* s2s_Wih = (const float*)d_in[20];
    const float* s2s_Whh = (const float*)d_in[21];
    const float* s2s_bih = (const float*)d_in[22];
    const float* s2s_bhh = (const float*)d_in[23];
    const float* post_W0 = (const float*)d_in[24];
    const float* post_b0 = (const float*)d_in[25];
    const float* post_W1 = (const float*)d_in[26];
    const float* post_b1 = (const float*)d_in[27];
    const float* post_W2 = (const float*)d_in[28];
    const float* post_b2 = (const float*)d_in[29];
    const float* post_W3 = (const float*)d_in[30];
    const float* post_b3 = (const float*)d_in[31];
    float* yout = (float*)d_out;

    char* wp = (char*)d_ws;
    auto take = [&](size_t bytes) -> char* {
        char* r = wp;
        wp += (bytes + 255) & ~(size_t)255;
        return r;
    };
    float* outA = (float*)take((size_t)NN * 64 * 4);
    float* agg  = (float*)take((size_t)NN * 64 * 4);
    __hip_bfloat16* W2F = (__hip_bfloat16*)take((size_t)3 * 64 * 4096 * 2);
    int* cnt_src  = (int*)take((size_t)NN * 4);
    int* cnt_dst  = (int*)take((size_t)NN * 4);
    int* csr_dst  = (int*)take((size_t)NN * BKT * 4);
    float* csr_ea = (float*)take((size_t)NN * BKT * 4);
    int* bstart   = (int*)take((size_t)NB * 4);
    int* bend     = (int*)take((size_t)NB * 4);
    float* WihT   = (float*)take((size_t)256 * 128 * 4);
    float* WhhT   = (float*)take((size_t)256 * 64 * 4);

    k_setup<<<224, 256, 0, stream>>>(enn_W2, W2F, agg, cnt_src, cnt_dst, bstart, bend);
    k_bucket<<<160, 256, 0, stream>>>(edge_idx, edge_attr, batch_map,
                                      s2s_Wih, s2s_Whh, WihT, WhhT,
                                      cnt_src, cnt_dst, csr_dst, csr_ea, bstart, bend);

    void* margs[] = { (void*)&x,
        (void*)&pre_W0, (void*)&pre_b0, (void*)&pre_W1, (void*)&pre_b1,
        (void*)&pre_W2, (void*)&pre_b2,
        (void*)&W2F, (void*)&enn_b2, (void*)&enn_W1, (void*)&enn_b1,
        (void*)&root_W, (void*)&conv_b,
        (void*)&gru_Wih, (void*)&gru_Whh, (void*)&gru_bih, (void*)&gru_bhh,
        (void*)&cnt_src, (void*)&cnt_dst, (void*)&csr_dst, (void*)&csr_ea,
        (void*)&agg, (void*)&outA };
    hipLaunchCooperativeKernel((void*)k_mega, dim3(512), dim3(256), margs, 0, stream);

    k_s2s_post<<<NB, 256, 0, stream>>>(outA, bstart, bend, WihT, WhhT, s2s_bih,
                                       s2s_bhh, post_W0, post_b0, post_W1, post_b1,
                                       post_W2, post_b2, post_W3, post_b3, yout);
}

// Round 8
// 488.154 us; speedup vs baseline: 1.9220x; 1.9220x over previous
//
#include <hip/hip_runtime.h>
#include <hip/hip_bf16.h>
#include <string.h>

#define NN   4096
#define NE   32768
#define NB   32
#define BKT  64   // per-src edge bucket capacity (deg ~ Poisson(8); P(>64) ~ 1e-30)
#define MSG_CHUNK 8

typedef __attribute__((ext_vector_type(8))) short short8;
typedef __attribute__((ext_vector_type(4))) float f4;

__device__ __forceinline__ float sigf(float x) { return 1.0f / (1.0f + __expf(-x)); }
__device__ __forceinline__ short f2bf(float f) {
    __hip_bfloat16 h = __float2bfloat16(f);
    short s;
    memcpy(&s, &h, sizeof(short));
    return s;
}

// ---------------- k_prep: zero/init + W2->W2F fragment repack + S2S transpose ------
// blocks 0..31: zero counters + both agg buffers, init batch ranges
// blocks 32..223: enn_W2 -> W2F fragment-packed bf16 (MFMA-ready)
// blocks 224..255: WihT/WhhT transpose for k_s2s_post
__global__ __launch_bounds__(256) void k_prep(const float* __restrict__ enn_W2,
        __hip_bfloat16* __restrict__ W2F,
        const float* __restrict__ Wih, const float* __restrict__ Whh,
        float* __restrict__ WihT, float* __restrict__ WhhT,
        float* __restrict__ aggAll,
        int* cnt_src, int* cnt_dst, int* bstart, int* bend) {
    int bid = blockIdx.x, t = threadIdx.x;
    if (bid < 32) {
        int i = bid * 256 + t;
        if (i < NN) cnt_src[i] = 0;
        else cnt_dst[i - NN] = 0;
        if (i < NB) { bstart[i] = 0x7FFFFFFF; bend[i] = 0; }
        float4 zz = {0.f, 0.f, 0.f, 0.f};
        float4* a4 = (float4*)aggAll;                 // 2*NN*64 floats = 131072 f4
        for (int z = i; z < 131072; z += 8192) a4[z] = zz;
    } else if (bid < 224) {
        __shared__ __hip_bfloat16 tile[4096];
        size_t base = (size_t)(bid - 32) * 4096;
        for (int i = t; i < 4096; i += 256) {
            int k = i >> 6, o = i & 63;
            int pos = ((o >> 4) << 10) | ((k >> 5) << 9) | (((k >> 3) & 3) << 7)
                    | ((o & 15) << 3) | (k & 7);
            tile[pos] = __float2bfloat16(enn_W2[base + i]);
        }
        __syncthreads();
        for (int i = t; i < 4096; i += 256) W2F[base + i] = tile[i];
    } else {
        int c0 = (bid - 224) * 8;
        for (int i = t; i < 1024; i += 256) {
            int c = c0 + (i >> 7), j = i & 127;
            WihT[(size_t)c * 128 + j] = Wih[(size_t)j * 256 + c];
        }
        for (int i = t; i < 512; i += 256) {
            int c = c0 + (i >> 6), j = i & 63;
            WhhT[(size_t)c * 64 + j] = Whh[(size_t)j * 256 + c];
        }
    }
}

// ---------------- k_bucket: bucket CSR fill + batch ranges (needs zeroed counters) --
__global__ __launch_bounds__(256) void k_bucket(const int* __restrict__ eidx,
        const float* __restrict__ ea, const int* __restrict__ bm,
        int* cnt_src, int* cnt_dst, int* csr_dst, float* csr_ea,
        int* bstart, int* bend) {
    int e = blockIdx.x * 256 + threadIdx.x;
    if (e < NE) {
        int s = eidx[e];
        int d = eidx[NE + e];
        int slot = atomicAdd(&cnt_src[s], 1);
        if (slot < BKT) {
            csr_dst[s * BKT + slot] = d;
            csr_ea[s * BKT + slot] = ea[e];
        }
        atomicAdd(&cnt_dst[d], 1);
    }
    if (e < NN) {
        int b = bm[e];
        atomicMin(&bstart[b], e);
        atomicMax(&bend[b], e + 1);
    }
}

// ---------------- k_flayer: [GRU(l-1) | pre-MLP] + P-MFMA + scatter (layer l) ------
// 512 blocks x 256 thr, block owns nodes 8b..8b+7 in every launch. l=0: pre-MLP(x)
// -> outs. l=1,2: GRU(l-1) from out_prev (global, written by F(l-1)) + agg_in
// (scatter(l-1) output; kernel boundary = sync), re-zeroing agg_in with plain
// stores (no in-kernel writer aliases it; scatter here targets agg_out). Then
// P-tile MFMA + per-edge scatter into agg_out — verbatim proven k_fused code.
__global__ __launch_bounds__(256, 2) void k_flayer(int l, const float* __restrict__ x,
        const float* __restrict__ out_prev, float* __restrict__ out_cur,
        float* __restrict__ agg_in, float* __restrict__ agg_out,
        const float* __restrict__ mW0, const float* __restrict__ mb0,
        const float* __restrict__ mW1, const float* __restrict__ mb1,
        const float* __restrict__ mW2, const float* __restrict__ mb2,
        const __hip_bfloat16* __restrict__ W2F, const float* __restrict__ enn_b2,
        const float* __restrict__ enn_W1, const float* __restrict__ enn_b1,
        const float* __restrict__ rootW, const float* __restrict__ convb,
        const float* __restrict__ gWih, const float* __restrict__ gWhh,
        const float* __restrict__ gbih, const float* __restrict__ gbhh,
        const int* __restrict__ cnt_src, const int* __restrict__ cnt_dst,
        const int* __restrict__ csr_dst, const float* __restrict__ csr_ea) {
    __shared__ float outs[8][68];
    __shared__ __hip_bfloat16 Pt[8 * 4096];           // 64 KB swizzled P tile
    __shared__ float wlds[4][MSG_CHUNK][64];          // 8 KB (aliased temps)
    int t = threadIdx.x, wave = t >> 6, lane = t & 63;
    int laneM = lane & 15, quad = lane >> 4;
    int n0 = blockIdx.x * 8;
    int j = lane;
    float* haL = &wlds[0][0][0];
    float* hbL = haL + 512;
    if (l == 0) {
        // ---- pre-MLP (same FMA order as proven k_setup path) ----
        float* xs = (float*)Pt;
        for (int i = t; i < 1024; i += 256) xs[i] = x[(size_t)n0 * 128 + i];
        __syncthreads();
        for (int u = 0; u < 2; ++u) {
            int nl = wave * 2 + u;
            const float* xr = xs + nl * 128;
            float s = mb0[j];
            #pragma unroll 8
            for (int k = 0; k < 128; ++k) s = fmaf(xr[k], mW0[k * 64 + j], s);
            haL[nl * 64 + j] = fmaxf(s, 0.f);
            s = mb1[j];
            #pragma unroll 8
            for (int k = 0; k < 64; ++k) s = fmaf(haL[nl * 64 + k], mW1[k * 64 + j], s);
            hbL[nl * 64 + j] = fmaxf(s, 0.f);
            s = mb2[j];
            #pragma unroll 8
            for (int k = 0; k < 64; ++k) s = fmaf(hbL[nl * 64 + k], mW2[k * 64 + j], s);
            outs[nl][j] = fmaxf(s, 0.f);
        }
        __syncthreads();
    } else {
        // ---- GRU(l-1) for own 8 nodes (same FMA order as proven k_gru) ----
        int gl = l - 1;
        const float* rootWl = rootW + (size_t)gl * 4096;
        const float* convbl = convb + gl * 64;
        const float* Wihl = gWih + (size_t)gl * 64 * 192;
        const float* Whhl = gWhh + (size_t)gl * 64 * 192;
        const float* bihl = gbih + gl * 192;
        const float* bhhl = gbhh + gl * 192;
        for (int i = t; i < 512; i += 256)
            outs[i >> 6][i & 63] = out_prev[(size_t)n0 * 64 + i];
        __syncthreads();
        float* scL = haL;
        for (int u = 0; u < 2; ++u) {
            int nl = wave * 2 + u;
            int n = n0 + nl;
            int dg = cnt_dst[n];
            float invd = 1.0f / (float)(dg > 0 ? dg : 1);
            float av = agg_in[(size_t)n * 64 + j];
            agg_in[(size_t)n * 64 + j] = 0.f;         // re-zero for layer l+1's scatter
            float s = av * invd + convbl[j];
            #pragma unroll 8
            for (int k = 0; k < 64; ++k) s = fmaf(outs[nl][k], rootWl[k * 64 + j], s);
            scL[nl * 64 + j] = fmaxf(s, 0.f);
        }
        __syncthreads();
        float o_new[2];
        for (int u = 0; u < 2; ++u) {
            int nl = wave * 2 + u;
            float hj = outs[nl][j];
            float gir = bihl[j], giz = bihl[64 + j], gin = bihl[128 + j];
            float ghr = bhhl[j], ghz = bhhl[64 + j], ghn = bhhl[128 + j];
            #pragma unroll 4
            for (int k = 0; k < 64; ++k) {
                float c = scL[nl * 64 + k], h = outs[nl][k];
                gir = fmaf(c, Wihl[k * 192 + j], gir);
                giz = fmaf(c, Wihl[k * 192 + 64 + j], giz);
                gin = fmaf(c, Wihl[k * 192 + 128 + j], gin);
                ghr = fmaf(h, Whhl[k * 192 + j], ghr);
                ghz = fmaf(h, Whhl[k * 192 + 64 + j], ghz);
                ghn = fmaf(h, Whhl[k * 192 + 128 + j], ghn);
            }
            float r = sigf(gir + ghr);
            float z = sigf(giz + ghz);
            float nn2 = tanhf(gin + r * ghn);
            o_new[u] = (1.f - z) * nn2 + z * hj;
        }
        __syncthreads();
        for (int u = 0; u < 2; ++u) outs[wave * 2 + u][j] = o_new[u];
        __syncthreads();
    }
    // write out(l) for next kernel's GRU (2 KB coalesced)
    for (int i = t; i < 512; i += 256)
        out_cur[(size_t)n0 * 64 + i] = outs[i >> 6][i & 63];
    // ---- P-tile MFMA + scatter (verbatim proven k_fused, layer l) ----
    const __hip_bfloat16* W2F_l = W2F + (size_t)l * 64 * 4096;
    const float* b2l = enn_b2 + (size_t)l * 4096;
    const float* W1l = enn_W1 + l * 64;
    const float* b1l = enn_b1 + l * 64;
    short8 a0, a1;
    {
        const float* ar = &outs[laneM & 7][quad * 8];
        #pragma unroll
        for (int q = 0; q < 8; ++q) a0[q] = f2bf(ar[q]);
        const float* ar2 = &outs[laneM & 7][32 + quad * 8];
        #pragma unroll
        for (int q = 0; q < 8; ++q) a1[q] = f2bf(ar2[q]);
    }
    float btr[2] = {0.f, 0.f};
    for (int k = 0; k < 64; ++k) {
        float bv = b2l[k * 64 + lane];
        #pragma unroll
        for (int u = 0; u < 2; ++u) btr[u] = fmaf(outs[wave * 2 + u][k], bv, btr[u]);
    }
    #pragma unroll 2
    for (int gp = 0; gp < 8; ++gp) {
        int gA = wave * 16 + gp * 2;
        const __hip_bfloat16* BgA = W2F_l + (size_t)gA * 4096;
        const __hip_bfloat16* BgB = BgA + 4096;
        int c = gA >> 3;
        int p = (gA >> 1) & 3;
        char* wb = (char*)Pt + (quad << 15) + (c << 10) + (laneM << 4)
                 + (((p ^ quad) & 3) << 2);
        #pragma unroll
        for (int sub = 0; sub < 4; ++sub) {
            short8 bA0 = *(const short8*)(BgA + sub * 1024 + lane * 8);
            short8 bA1 = *(const short8*)(BgA + sub * 1024 + 512 + lane * 8);
            short8 bB0 = *(const short8*)(BgB + sub * 1024 + lane * 8);
            short8 bB1 = *(const short8*)(BgB + sub * 1024 + 512 + lane * 8);
            f4 accA = {0.f, 0.f, 0.f, 0.f}, accB = {0.f, 0.f, 0.f, 0.f};
            accA = __builtin_amdgcn_mfma_f32_16x16x32_bf16(a0, bA0, accA, 0, 0, 0);
            accA = __builtin_amdgcn_mfma_f32_16x16x32_bf16(a1, bA1, accA, 0, 0, 0);
            accB = __builtin_amdgcn_mfma_f32_16x16x32_bf16(a0, bB0, accB, 0, 0, 0);
            accB = __builtin_amdgcn_mfma_f32_16x16x32_bf16(a1, bB1, accB, 0, 0, 0);
            if (quad < 2) {
                char* wbs = wb + (sub << 8);
                #pragma unroll
                for (int r = 0; r < 4; ++r) {
                    unsigned pk = (unsigned)(unsigned short)f2bf(accA[r])
                                | ((unsigned)(unsigned short)f2bf(accB[r]) << 16);
                    *(unsigned*)(wbs + (r << 13)) = pk;
                }
            }
        }
    }
    __syncthreads();
    float w1v = W1l[lane], b1v = b1l[lane];
    for (int u = 0; u < 2; ++u) {
        int nloc = wave * 2 + u;
        int n = n0 + nloc;
        int deg = cnt_src[n];
        if (deg > BKT) deg = BKT;
        if (deg <= 0) continue;
        int wq = nloc >> 2;
        float preg[64];
        const char* Pn = (const char*)Pt + (nloc << 13);
        #pragma unroll
        for (int c = 0; c < 8; ++c) {
            uint4 vv = *(const uint4*)(Pn + (c << 10) + (lane << 4));
            unsigned d0 = vv.x, d1 = vv.y, d2 = vv.z, d3 = vv.w;
            if (wq & 1) { unsigned tt = d0; d0 = d1; d1 = tt; tt = d2; d2 = d3; d3 = tt; }
            union { unsigned u2; float f; } cv;
            cv.u2 = d0 << 16;          preg[c * 8 + 0] = cv.f;
            cv.u2 = d0 & 0xFFFF0000u;  preg[c * 8 + 1] = cv.f;
            cv.u2 = d1 << 16;          preg[c * 8 + 2] = cv.f;
            cv.u2 = d1 & 0xFFFF0000u;  preg[c * 8 + 3] = cv.f;
            cv.u2 = d2 << 16;          preg[c * 8 + 4] = cv.f;
            cv.u2 = d2 & 0xFFFF0000u;  preg[c * 8 + 5] = cv.f;
            cv.u2 = d3 << 16;          preg[c * 8 + 6] = cv.f;
            cv.u2 = d3 & 0xFFFF0000u;  preg[c * 8 + 7] = cv.f;
        }
        float bt = btr[u];
        const int* bdst = csr_dst + n * BKT;
        const float* bea = csr_ea + n * BKT;
        for (int c0 = 0; c0 < deg; c0 += MSG_CHUNK) {
            int cc = deg - c0;
            if (cc > MSG_CHUNK) cc = MSG_CHUNK;
            int dl = 0; float el = 0.f;
            if (lane < cc) { dl = bdst[c0 + lane]; el = bea[c0 + lane]; }
            for (int si = 0; si < cc; ++si) {
                float eav = __shfl(el, si, 64);
                wlds[wave][si][lane] = fmaxf(fmaf(eav, w1v, b1v), 0.f);
            }
            for (int i = 0; i < cc; ++i) {
                int dst = __shfl(dl, i, 64);
                const float* wr = wlds[wave][i];
                float acc0 = bt, acc1 = 0.f, acc2 = 0.f, acc3 = 0.f;
                #pragma unroll
                for (int g = 0; g < 64; g += 16) {
                    float4 w0 = *(const float4*)(wr + g);
                    float4 w1 = *(const float4*)(wr + g + 4);
                    float4 w2 = *(const float4*)(wr + g + 8);
                    float4 w3 = *(const float4*)(wr + g + 12);
                    acc0 = fmaf(w0.x, preg[g], acc0);
                    acc0 = fmaf(w0.y, preg[g + 1], acc0);
                    acc0 = fmaf(w0.z, preg[g + 2], acc0);
                    acc0 = fmaf(w0.w, preg[g + 3], acc0);
                    acc1 = fmaf(w1.x, preg[g + 4], acc1);
                    acc1 = fmaf(w1.y, preg[g + 5], acc1);
                    acc1 = fmaf(w1.z, preg[g + 6], acc1);
                    acc1 = fmaf(w1.w, preg[g + 7], acc1);
                    acc2 = fmaf(w2.x, preg[g + 8], acc2);
                    acc2 = fmaf(w2.y, preg[g + 9], acc2);
                    acc2 = fmaf(w2.z, preg[g + 10], acc2);
                    acc2 = fmaf(w2.w, preg[g + 11], acc2);
                    acc3 = fmaf(w3.x, preg[g + 12], acc3);
                    acc3 = fmaf(w3.y, preg[g + 13], acc3);
                    acc3 = fmaf(w3.z, preg[g + 14], acc3);
                    acc3 = fmaf(w3.w, preg[g + 15], acc3);
                }
                float acc = (acc0 + acc1) + (acc2 + acc3);
                atomicAdd(&agg_out[(size_t)dst * 64 + lane], acc);
            }
        }
    }
}

// ---------------- k_s2s_post: GRU(2) for own rows + Set2Set + post-MLP --------------
// One block = one batch. Prologue computes the FINAL GRU for this block's node rows
// (wave-private rows, no barriers; same FMA order as k_gru) writing directly into
// cacheT (rows >=192 spill to outScr global). Then the proven burst s2s + post-MLP.
__global__ __launch_bounds__(256, 1) void k_s2s_post(const float* __restrict__ outPrev,
        const float* __restrict__ aggIn, const int* __restrict__ cnt_dst,
        const float* __restrict__ rootW2, const float* __restrict__ convb2,
        const float* __restrict__ Wih2, const float* __restrict__ Whh2,
        const float* __restrict__ bih2, const float* __restrict__ bhh2,
        float* __restrict__ outScr,
        const int* __restrict__ bstart, const int* __restrict__ bend,
        const float* __restrict__ WihT, const float* __restrict__ WhhT,
        const float* __restrict__ bih, const float* __restrict__ bhh,
        const float* __restrict__ pW0, const float* __restrict__ pb0,
        const float* __restrict__ pW1, const float* __restrict__ pb1,
        const float* __restrict__ pW2, const float* __restrict__ pb2,
        const float* __restrict__ pW3, const float* __restrict__ pb3,
        float* __restrict__ y) {
    __shared__ float cacheT[64 * 193];     // transposed node tile (49.4 KB)
    __shared__ float wpost[16448];         // pW0|pW1|pW2|pW3 (64.3 KB)
    __shared__ float sh4[4][64], sc4[4][64];
    __shared__ float qs[128];
    __shared__ float hh_l[64];
    __shared__ float gates_l[256];
    __shared__ float ebuf[1024];
    __shared__ float redw[4], redw2[4];
    __shared__ float redbuf[4][64];
    __shared__ float tmp64[64];
    int t = threadIdx.x, wave = t >> 6, lane = t & 63;
    int b = blockIdx.x;
    int s0 = bstart[b], e0 = bend[b];
    int cnt = e0 - s0;
    if (cnt < 0) cnt = 0;
    if (cnt > 1024) cnt = 1024;
    int ccnt = cnt < 192 ? cnt : 192;
    int j = lane;
    // ---- GRU(2) for this block's rows: 4 rows/pass, wave-private (no barriers) ----
    for (int base = 0; base < cnt; base += 4) {
        int row = base + wave;
        bool ok = row < cnt;
        int n = s0 + (ok ? row : 0);
        float hj = ok ? outPrev[(size_t)n * 64 + j] : 0.f;
        float av = ok ? aggIn[(size_t)n * 64 + j] : 0.f;
        int dg = ok ? cnt_dst[n] : 1;
        sh4[wave][j] = hj;
        float invd = 1.0f / (float)(dg > 0 ? dg : 1);
        float s = av * invd + convb2[j];
        #pragma unroll 8
        for (int k = 0; k < 64; ++k) s = fmaf(sh4[wave][k], rootW2[k * 64 + j], s);
        sc4[wave][j] = fmaxf(s, 0.f);
        float gir = bih2[j], giz = bih2[64 + j], gin = bih2[128 + j];
        float ghr = bhh2[j], ghz = bhh2[64 + j], ghn = bhh2[128 + j];
        #pragma unroll 4
        for (int k = 0; k < 64; ++k) {
            float c = sc4[wave][k], h = sh4[wave][k];
            gir = fmaf(c, Wih2[k * 192 + j], gir);
            giz = fmaf(c, Wih2[k * 192 + 64 + j], giz);
            gin = fmaf(c, Wih2[k * 192 + 128 + j], gin);
            ghr = fmaf(h, Whh2[k * 192 + j], ghr);
            ghz = fmaf(h, Whh2[k * 192 + 64 + j], ghz);
            ghn = fmaf(h, Whh2[k * 192 + 128 + j], ghn);
        }
        float r = sigf(gir + ghr);
        float z = sigf(giz + ghz);
        float nn2 = tanhf(gin + r * ghn);
        float o = (1.f - z) * nn2 + z * hj;
        if (ok) {
            if (row < 192) cacheT[j * 193 + row] = o;      // banks (j+row)%32: free
            else outScr[(size_t)n * 64 + j] = o;
        }
    }
    // ---- post-MLP weights -> LDS burst ----
    {
        float4* wp4 = (float4*)wpost;
        #pragma unroll
        for (int i = 0; i < 8; ++i) { int v = t + i * 256; wp4[v] = ((const float4*)pW0)[v]; }
        #pragma unroll
        for (int i = 0; i < 4; ++i) { int v = t + i * 256; wp4[2048 + v] = ((const float4*)pW1)[v]; }
        #pragma unroll
        for (int i = 0; i < 4; ++i) { int v = t + i * 256; wp4[3072 + v] = ((const float4*)pW2)[v]; }
        if (t < 16) wp4[4096 + t] = ((const float4*)pW3)[t];
    }
    const float4* wihT4 = (const float4*)(WihT + (size_t)t * 128);
    const float4* whhT4 = (const float4*)(WhhT + (size_t)t * 64);
    float bsum = bih[t] + bhh[t];
    float ccr = 0.f;
    if (t < 128) qs[t] = 0.f;
    if (t < 64) hh_l[t] = 0.f;
    __syncthreads();
    const float4* qs4 = (const float4*)qs;
    const float4* hh4 = (const float4*)hh_l;
    for (int step = 0; step < 3; ++step) {
        float g0 = bsum, g1 = 0.f, g2 = 0.f, g3 = 0.f;
        #pragma unroll
        for (int jq = 0; jq < 32; ++jq) {
            float4 w = wihT4[jq];
            float4 v = qs4[jq];
            g0 = fmaf(v.x, w.x, g0);
            g1 = fmaf(v.y, w.y, g1);
            g2 = fmaf(v.z, w.z, g2);
            g3 = fmaf(v.w, w.w, g3);
        }
        #pragma unroll
        for (int jq = 0; jq < 16; ++jq) {
            float4 w = whhT4[jq];
            float4 v = hh4[jq];
            g0 = fmaf(v.x, w.x, g0);
            g1 = fmaf(v.y, w.y, g1);
            g2 = fmaf(v.z, w.z, g2);
            g3 = fmaf(v.w, w.w, g3);
        }
        gates_l[t] = (g0 + g1) + (g2 + g3);
        __syncthreads();                                     // B1: gates ready
        if (t < 64) {
            float cn = sigf(gates_l[64 + t]) * ccr
                     + sigf(gates_l[t]) * tanhf(gates_l[128 + t]);
            ccr = cn;
            hh_l[t] = sigf(gates_l[192 + t]) * tanhf(cn);
        }
        __syncthreads();                                     // B2: hh ready
        for (int idx = t; idx < cnt; idx += 256) {
            float s0a = 0.f, s1a = 0.f, s2a = 0.f, s3a = 0.f;
            if (idx < 192) {
                #pragma unroll
                for (int dq = 0; dq < 16; ++dq) {
                    float4 h = hh4[dq];
                    s0a = fmaf(cacheT[(dq * 4 + 0) * 193 + idx], h.x, s0a);
                    s1a = fmaf(cacheT[(dq * 4 + 1) * 193 + idx], h.y, s1a);
                    s2a = fmaf(cacheT[(dq * 4 + 2) * 193 + idx], h.z, s2a);
                    s3a = fmaf(cacheT[(dq * 4 + 3) * 193 + idx], h.w, s3a);
                }
            } else {
                const float* row = outScr + (size_t)(s0 + idx) * 64;
                #pragma unroll
                for (int dq = 0; dq < 16; ++dq) {
                    float4 h = hh4[dq];
                    s0a = fmaf(row[dq * 4 + 0], h.x, s0a);
                    s1a = fmaf(row[dq * 4 + 1], h.y, s1a);
                    s2a = fmaf(row[dq * 4 + 2], h.z, s2a);
                    s3a = fmaf(row[dq * 4 + 3], h.w, s3a);
                }
            }
            ebuf[idx] = (s0a + s1a) + (s2a + s3a);
        }
        __syncthreads();                                     // B3: e ready
        float lm = -3.0e38f;
        for (int idx = t; idx < cnt; idx += 256) lm = fmaxf(lm, ebuf[idx]);
        #pragma unroll
        for (int off = 32; off > 0; off >>= 1) lm = fmaxf(lm, __shfl_xor(lm, off, 64));
        if (lane == 0) redw[wave] = lm;
        __syncthreads();                                     // B4: wave maxes
        float m = fmaxf(fmaxf(redw[0], redw[1]), fmaxf(redw[2], redw[3]));
        float ls = 0.f;
        for (int idx = t; idx < cnt; idx += 256) {
            float a = __expf(ebuf[idx] - m);
            ebuf[idx] = a;
            ls += a;
        }
        #pragma unroll
        for (int off = 32; off > 0; off >>= 1) ls += __shfl_xor(ls, off, 64);
        if (lane == 0) redw2[wave] = ls;
        __syncthreads();                                     // B5: a's + wave sums
        float ssum = (redw2[0] + redw2[1]) + (redw2[2] + redw2[3]);
        float inv = (cnt > 0) ? 1.f / ssum : 0.f;
        float r0 = 0.f;
        for (int row = wave; row < ccnt; row += 4)
            r0 = fmaf(ebuf[row], cacheT[lane * 193 + row], r0);
        for (int row = 192 + wave; row < cnt; row += 4)
            r0 = fmaf(ebuf[row], outScr[(size_t)(s0 + row) * 64 + lane], r0);
        redbuf[wave][lane] = r0;
        __syncthreads();                                     // B6: wave partials
        if (t < 64) {
            float s = ((redbuf[0][t] + redbuf[1][t]) + (redbuf[2][t] + redbuf[3][t]));
            qs[64 + t] = s * inv;
            qs[t] = hh_l[t];
        }
        __syncthreads();                                     // B7: qs ready
    }
    if (t < 64) {
        float s = pb0[t];
        #pragma unroll 4
        for (int k = 0; k < 128; ++k) s = fmaf(qs[k], wpost[k * 64 + t], s);
        tmp64[t] = fmaxf(s, 0.f);
    }
    __syncthreads();
    float h1v = 0.f;
    if (t < 64) {
        float s = pb1[t];
        #pragma unroll 4
        for (int k = 0; k < 64; ++k) s = fmaf(tmp64[k], wpost[8192 + k * 64 + t], s);
        h1v = fmaxf(s, 0.f);
    }
    __syncthreads();
    if (t < 64) tmp64[t] = h1v;
    __syncthreads();
    if (t < 64) {
        float s = pb2[t];
        #pragma unroll 4
        for (int k = 0; k < 64; ++k) s = fmaf(tmp64[k], wpost[12288 + k * 64 + t], s);
        gates_l[t] = fmaxf(s, 0.f) * wpost[16384 + t];
    }
    __syncthreads();
    if (t == 0) {
        float yy = pb3[0];
        for (int k = 0; k < 64; ++k) yy += gates_l[k];
        y[b] = yy;
    }
}

// ---------------- host ----------------

extern "C" void kernel_launch(void* const* d_in, const int* in_sizes, int n_in,
                              void* d_out, int out_size, void* d_ws, size_t ws_size,
                              hipStream_t stream) {
    const float* x         = (const float*)d_in[0];
    const float* edge_attr = (const float*)d_in[1];
    const int*   edge_idx  = (const int*)d_in[2];
    const int*   batch_map = (const int*)d_in[3];
    const float* pre_W0 = (const float*)d_in[4];
    const float* pre_b0 = (const float*)d_in[5];
    const float* pre_W1 = (const float*)d_in[6];
    const float* pre_b1 = (const float*)d_in[7];
    const float* pre_W2 = (const float*)d_in[8];
    const float* pre_b2 = (const float*)d_in[9];
    const float* enn_W1 = (const float*)d_in[10];
    const float* enn_b1 = (const float*)d_in[11];
    const float* enn_W2 = (const float*)d_in[12];
    const float* enn_b2 = (const float*)d_in[13];
    const float* root_W = (const float*)d_in[14];
    const float* conv_b = (const float*)d_in[15];
    const float* gru_Wih = (const float*)d_in[16];
    const float* gru_Whh = (const float*)d_in[17];
    const float* gru_bih = (const float*)d_in[18];
    const float* gru_bhh = (const float*)d_in[19];
    const float* s2s_Wih = (const float*)d_in[20];
    const float* s2s_Whh = (const float*)d_in[21];
    const float* s2s_bih = (const float*)d_in[22];
    const float* s2s_bhh = (const float*)d_in[23];
    const float* post_W0 = (const float*)d_in[24];
    const float* post_b0 = (const float*)d_in[25];
    const float* post_W1 = (const float*)d_in[26];
    const float* post_b1 = (const float*)d_in[27];
    const float* post_W2 = (const float*)d_in[28];
    const float* post_b2 = (const float*)d_in[29];
    const float* post_W3 = (const float*)d_in[30];
    const float* post_b3 = (const float*)d_in[31];
    float* yout = (float*)d_out;

    char* wp = (char*)d_ws;
    auto take = [&](size_t bytes) -> char* {
        char* r = wp;
        wp += (bytes + 255) & ~(size_t)255;
        return r;
    };
    float* outA = (float*)take((size_t)NN * 64 * 4);
    float* outB = (float*)take((size_t)NN * 64 * 4);
    float* aggP = (float*)take((size_t)2 * NN * 64 * 4);   // agg0 | agg1
    __hip_bfloat16* W2F = (__hip_bfloat16*)take((size_t)3 * 64 * 4096 * 2);
    int* cnt_src  = (int*)take((size_t)NN * 4);
    int* cnt_dst  = (int*)take((size_t)NN * 4);
    int* csr_dst  = (int*)take((size_t)NN * BKT * 4);
    float* csr_ea = (float*)take((size_t)NN * BKT * 4);
    int* bstart   = (int*)take((size_t)NB * 4);
    int* bend     = (int*)take((size_t)NB * 4);
    float* WihT   = (float*)take((size_t)256 * 128 * 4);
    float* WhhT   = (float*)take((size_t)256 * 64 * 4);
    float* agg0 = aggP;
    float* agg1 = aggP + (size_t)NN * 64;

    k_prep<<<256, 256, 0, stream>>>(enn_W2, W2F, s2s_Wih, s2s_Whh, WihT, WhhT,
                                    aggP, cnt_src, cnt_dst, bstart, bend);
    k_bucket<<<128, 256, 0, stream>>>(edge_idx, edge_attr, batch_map,
                                      cnt_src, cnt_dst, csr_dst, csr_ea, bstart, bend);

    // F0: pre-MLP -> out0(outA), scatter0 -> agg0
    k_flayer<<<512, 256, 0, stream>>>(0, x, outA, outA, agg1, agg0,
        pre_W0, pre_b0, pre_W1, pre_b1, pre_W2, pre_b2,
        W2F, enn_b2, enn_W1, enn_b1, root_W, conv_b,
        gru_Wih, gru_Whh, gru_bih, gru_bhh,
        cnt_src, cnt_dst, csr_dst, csr_ea);
    // F1: GRU0(outA, agg0) -> out1(outB), scatter1 -> agg1
    k_flayer<<<512, 256, 0, stream>>>(1, x, outA, outB, agg0, agg1,
        pre_W0, pre_b0, pre_W1, pre_b1, pre_W2, pre_b2,
        W2F, enn_b2, enn_W1, enn_b1, root_W, conv_b,
        gru_Wih, gru_Whh, gru_bih, gru_bhh,
        cnt_src, cnt_dst, csr_dst, csr_ea);
    // F2: GRU1(outB, agg1) -> out2(outA), scatter2 -> agg0
    k_flayer<<<512, 256, 0, stream>>>(2, x, outB, outA, agg1, agg0,
        pre_W0, pre_b0, pre_W1, pre_b1, pre_W2, pre_b2,
        W2F, enn_b2, enn_W1, enn_b1, root_W, conv_b,
        gru_Wih, gru_Whh, gru_bih, gru_bhh,
        cnt_src, cnt_dst, csr_dst, csr_ea);
    // s2s: GRU2(outA, agg0) inline + Set2Set + post-MLP
    k_s2s_post<<<NB, 256, 0, stream>>>(outA, agg0, cnt_dst,
        root_W + 2 * 4096, conv_b + 2 * 64,
        gru_Wih + 2 * 64 * 192, gru_Whh + 2 * 64 * 192,
        gru_bih + 2 * 192, gru_bhh + 2 * 192, outB,
        bstart, bend, WihT, WhhT, s2s_bih, s2s_bhh,
        post_W0, post_b0, post_W1, post_b1,
        post_W2, post_b2, post_W3, post_b3, yout);
}

// Round 9
// 329.611 us; speedup vs baseline: 2.8464x; 1.4810x over previous
//
#include <hip/hip_runtime.h>
#include <hip/hip_bf16.h>
#include <string.h>

#define NN   4096
#define NE   32768
#define NB   32
#define BKT  64   // per-src edge bucket capacity (deg ~ Poisson(8); P(>64) ~ 1e-30)
#define MSG_CHUNK 8

typedef __attribute__((ext_vector_type(8))) short short8;
typedef __attribute__((ext_vector_type(4))) float f4;

__device__ __forceinline__ float sigf(float x) { return 1.0f / (1.0f + __expf(-x)); }
__device__ __forceinline__ short f2bf(float f) {
    __hip_bfloat16 h = __float2bfloat16(f);
    short s;
    memcpy(&s, &h, sizeof(short));
    return s;
}

// ---------------- k_setup: init + W2->W2F fragment repack + pre-MLP ----------------
__global__ __launch_bounds__(256) void k_setup(const float* __restrict__ x,
        const float* __restrict__ W0, const float* __restrict__ b0,
        const float* __restrict__ W1, const float* __restrict__ b1,
        const float* __restrict__ W2, const float* __restrict__ b2,
        const float* __restrict__ enn_W2, __hip_bfloat16* __restrict__ W2F,
        float* __restrict__ out, float* __restrict__ agg,
        int* cnt_src, int* cnt_dst, int* bstart, int* bend) {
    int bid = blockIdx.x, t = threadIdx.x;
    if (bid < 32) {
        int i = bid * 256 + t;
        if (i < NN) cnt_src[i] = 0;
        else cnt_dst[i - NN] = 0;
        if (i < NB) { bstart[i] = 0x7FFFFFFF; bend[i] = 0; }
    } else if (bid < 224) {
        __shared__ __hip_bfloat16 tile[4096];
        size_t base = (size_t)(bid - 32) * 4096;
        for (int i = t; i < 4096; i += 256) {
            int k = i >> 6, o = i & 63;
            int pos = ((o >> 4) << 10) | ((k >> 5) << 9) | (((k >> 3) & 3) << 7)
                    | ((o & 15) << 3) | (k & 7);
            tile[pos] = __float2bfloat16(enn_W2[base + i]);
        }
        __syncthreads();
        for (int i = t; i < 4096; i += 256) W2F[base + i] = tile[i];
    } else {
        __shared__ float xr[4][128], ha[4][64], hb[4][64];
        int w = t >> 6, j = t & 63;
        int n = (bid - 224) * 4 + w;
        xr[w][j] = x[(size_t)n * 128 + j];
        xr[w][64 + j] = x[(size_t)n * 128 + 64 + j];
        agg[(size_t)n * 64 + j] = 0.f;
        float s = b0[j];
        #pragma unroll 8
        for (int k = 0; k < 128; ++k) s = fmaf(xr[w][k], W0[k * 64 + j], s);
        ha[w][j] = fmaxf(s, 0.f);
        s = b1[j];
        #pragma unroll 8
        for (int k = 0; k < 64; ++k) s = fmaf(ha[w][k], W1[k * 64 + j], s);
        hb[w][j] = fmaxf(s, 0.f);
        s = b2[j];
        #pragma unroll 8
        for (int k = 0; k < 64; ++k) s = fmaf(hb[w][k], W2[k * 64 + j], s);
        out[(size_t)n * 64 + j] = fmaxf(s, 0.f);
    }
}

// ---------------- k_bucket: bucket CSR fill + batch ranges + S2S weight transpose ---
__global__ __launch_bounds__(256) void k_bucket(const int* __restrict__ eidx,
        const float* __restrict__ ea, const int* __restrict__ bm,
        const float* __restrict__ Wih, const float* __restrict__ Whh,
        float* __restrict__ WihT, float* __restrict__ WhhT,
        int* cnt_src, int* cnt_dst, int* csr_dst, float* csr_ea,
        int* bstart, int* bend) {
    int t = threadIdx.x;
    if (blockIdx.x >= 128) {
        int c0 = (blockIdx.x - 128) * 8;
        for (int i = t; i < 1024; i += 256) {
            int c = c0 + (i >> 7), j = i & 127;
            WihT[(size_t)c * 128 + j] = Wih[(size_t)j * 256 + c];
        }
        for (int i = t; i < 512; i += 256) {
            int c = c0 + (i >> 6), j = i & 63;
            WhhT[(size_t)c * 64 + j] = Whh[(size_t)j * 256 + c];
        }
        return;
    }
    int e = blockIdx.x * 256 + t;
    if (e < NE) {
        int s = eidx[e];
        int d = eidx[NE + e];
        int slot = atomicAdd(&cnt_src[s], 1);
        if (slot < BKT) {
            csr_dst[s * BKT + slot] = d;
            csr_ea[s * BKT + slot] = ea[e];
        }
        atomicAdd(&cnt_dst[d], 1);
    }
    if (e < NN) {
        int b = bm[e];
        atomicMin(&bstart[b], e);
        atomicMax(&bend[b], e + 1);
    }
}

// ---------------- k_fused: half-g P-tile MFMA in LDS + message scatter --------------
// Block = (8-node tile) x (g-chunk of 32). ntile = bid>>1, gc = bid&1. Grid 1024.
// LDS 38.4 KB -> 4 blocks/CU (16 waves/CU, 2x the R6 full-g version); atomics 2x/edge
// (partial g-sums; R2 showed 4x was the limit, 2x is cheap). B-traffic unchanged.
// Phase 1: wave w owns gl in [8w,8w+8) (one octet, 4 pairs). Node region = 4 KB:
//   addr(n,gl,o) = n*4096 + (gl>>3)*1024 + o*16 + pair-dword, dword XOR'd by writer
//   quad for conflict-free ds_write. Phase 2: wave w scatters srcs {2w,2w+1} over
//   this block's 32 g; quad-XOR undone by pair-swap when writer quad (nloc>>2) is odd.
// BT contributed only by gc==0 (proven R2 pattern).
__global__ __launch_bounds__(256, 4) void k_fused(const float* __restrict__ out,
        const __hip_bfloat16* __restrict__ W2F_l, const float* __restrict__ b2l,
        const float* __restrict__ W1l, const float* __restrict__ b1l,
        const int* __restrict__ cnt_src, const int* __restrict__ csr_dst,
        const float* __restrict__ csr_ea, float* __restrict__ agg) {
    __shared__ __hip_bfloat16 Pt[8 * 2048];           // 32 KB swizzled half-g P tile
    __shared__ float outs[8][68];                     // fp32 node tile (padded)
    __shared__ float wlds[4][MSG_CHUNK][32];          // 4 KB We1 buffers (wave-private)
    int t = threadIdx.x, wave = t >> 6, lane = t & 63;
    int laneM = lane & 15, quad = lane >> 4;
    int ntile = blockIdx.x >> 1, gc = blockIdx.x & 1;
    int n0 = ntile * 8;
    for (int i = t; i < 512; i += 256) outs[i >> 6][i & 63] = out[(size_t)n0 * 64 + i];
    __syncthreads();
    // A fragments (rows = 8 nodes, rows 8..15 duplicated; K = 64)
    short8 a0, a1;
    {
        const float* ar = &outs[laneM & 7][quad * 8];
        #pragma unroll
        for (int j = 0; j < 8; ++j) a0[j] = f2bf(ar[j]);
        const float* ar2 = &outs[laneM & 7][32 + quad * 8];
        #pragma unroll
        for (int j = 0; j < 8; ++j) a1[j] = f2bf(ar2[j]);
    }
    // BT (fp32, same summation order as proven); only gc==0 contributes it
    float btr[2] = {0.f, 0.f};
    if (gc == 0) {
        for (int k = 0; k < 64; ++k) {
            float bv = b2l[k * 64 + lane];
            #pragma unroll
            for (int u = 0; u < 2; ++u) btr[u] = fmaf(outs[wave * 2 + u][k], bv, btr[u]);
        }
    }
    // Phase 1: wave w owns gl in [8w, 8w+8) (octet c = wave), 4 adjacent pairs
    #pragma unroll
    for (int gp = 0; gp < 4; ++gp) {
        int glA = wave * 8 + gp * 2;                   // even local g
        int gA = gc * 32 + glA;
        const __hip_bfloat16* BgA = W2F_l + (size_t)gA * 4096;
        const __hip_bfloat16* BgB = BgA + 4096;
        int c = wave;                                  // glA>>3
        int p = gp;                                    // (glA>>1)&3
        char* wb = (char*)Pt + (quad << 14) + (c << 10) + (laneM << 4)
                 + (((p ^ quad) & 3) << 2);
        #pragma unroll
        for (int sub = 0; sub < 4; ++sub) {
            short8 bA0 = *(const short8*)(BgA + sub * 1024 + lane * 8);
            short8 bA1 = *(const short8*)(BgA + sub * 1024 + 512 + lane * 8);
            short8 bB0 = *(const short8*)(BgB + sub * 1024 + lane * 8);
            short8 bB1 = *(const short8*)(BgB + sub * 1024 + 512 + lane * 8);
            f4 accA = {0.f, 0.f, 0.f, 0.f}, accB = {0.f, 0.f, 0.f, 0.f};
            accA = __builtin_amdgcn_mfma_f32_16x16x32_bf16(a0, bA0, accA, 0, 0, 0);
            accA = __builtin_amdgcn_mfma_f32_16x16x32_bf16(a1, bA1, accA, 0, 0, 0);
            accB = __builtin_amdgcn_mfma_f32_16x16x32_bf16(a0, bB0, accB, 0, 0, 0);
            accB = __builtin_amdgcn_mfma_f32_16x16x32_bf16(a1, bB1, accB, 0, 0, 0);
            if (quad < 2) {                            // nodes = quad*4+r in 0..7
                char* wbs = wb + (sub << 8);           // o += 16 -> 256 B
                #pragma unroll
                for (int r = 0; r < 4; ++r) {
                    unsigned pk = (unsigned)(unsigned short)f2bf(accA[r])
                                | ((unsigned)(unsigned short)f2bf(accB[r]) << 16);
                    *(unsigned*)(wbs + (r << 12)) = pk;    // node stride 4096 B
                }
            }
        }
    }
    __syncthreads();
    // Phase 2: partial-g message scatter, 2 srcs per wave, one atomic per (edge, gc)
    float w1v = (lane < 32) ? W1l[gc * 32 + lane] : 0.f;
    float b1v = (lane < 32) ? b1l[gc * 32 + lane] : 0.f;
    for (int u = 0; u < 2; ++u) {
        int nloc = wave * 2 + u;
        int n = n0 + nloc;
        int deg = cnt_src[n];
        if (deg > BKT) deg = BKT;
        if (deg <= 0) continue;
        int wq = nloc >> 2;                            // writer quad (0 or 1)
        float preg[32];                                // P[n, gl 0..31, o=lane]
        const char* Pn = (const char*)Pt + (nloc << 12);
        #pragma unroll
        for (int c2 = 0; c2 < 4; ++c2) {
            uint4 vv = *(const uint4*)(Pn + (c2 << 10) + (lane << 4));
            unsigned d0 = vv.x, d1 = vv.y, d2 = vv.z, d3 = vv.w;
            if (wq & 1) { unsigned tt = d0; d0 = d1; d1 = tt; tt = d2; d2 = d3; d3 = tt; }
            union { unsigned u2; float f; } cv;
            cv.u2 = d0 << 16;          preg[c2 * 8 + 0] = cv.f;
            cv.u2 = d0 & 0xFFFF0000u;  preg[c2 * 8 + 1] = cv.f;
            cv.u2 = d1 << 16;          preg[c2 * 8 + 2] = cv.f;
            cv.u2 = d1 & 0xFFFF0000u;  preg[c2 * 8 + 3] = cv.f;
            cv.u2 = d2 << 16;          preg[c2 * 8 + 4] = cv.f;
            cv.u2 = d2 & 0xFFFF0000u;  preg[c2 * 8 + 5] = cv.f;
            cv.u2 = d3 << 16;          preg[c2 * 8 + 6] = cv.f;
            cv.u2 = d3 & 0xFFFF0000u;  preg[c2 * 8 + 7] = cv.f;
        }
        float bt = btr[u];                             // 0 unless gc==0
        const int* bdst = csr_dst + n * BKT;
        const float* bea = csr_ea + n * BKT;
        for (int c0 = 0; c0 < deg; c0 += MSG_CHUNK) {
            int cc = deg - c0;
            if (cc > MSG_CHUNK) cc = MSG_CHUNK;
            int dl = 0; float el = 0.f;
            if (lane < cc) { dl = bdst[c0 + lane]; el = bea[c0 + lane]; }
            for (int si = 0; si < cc; ++si) {
                float eav = __shfl(el, si, 64);
                if (lane < 32)
                    wlds[wave][si][lane] = fmaxf(fmaf(eav, w1v, b1v), 0.f);  // lane = gl
            }
            for (int i = 0; i < cc; ++i) {
                int dst = __shfl(dl, i, 64);
                const float* wr = wlds[wave][i];
                float acc0 = bt, acc1 = 0.f, acc2 = 0.f, acc3 = 0.f;
                #pragma unroll
                for (int g = 0; g < 32; g += 16) {
                    float4 w0 = *(const float4*)(wr + g);
                    float4 w1 = *(const float4*)(wr + g + 4);
                    float4 w2 = *(const float4*)(wr + g + 8);
                    float4 w3 = *(const float4*)(wr + g + 12);
                    acc0 = fmaf(w0.x, preg[g], acc0);
                    acc0 = fmaf(w0.y, preg[g + 1], acc0);
                    acc0 = fmaf(w0.z, preg[g + 2], acc0);
                    acc0 = fmaf(w0.w, preg[g + 3], acc0);
                    acc1 = fmaf(w1.x, preg[g + 4], acc1);
                    acc1 = fmaf(w1.y, preg[g + 5], acc1);
                    acc1 = fmaf(w1.z, preg[g + 6], acc1);
                    acc1 = fmaf(w1.w, preg[g + 7], acc1);
                    acc2 = fmaf(w2.x, preg[g + 8], acc2);
                    acc2 = fmaf(w2.y, preg[g + 9], acc2);
                    acc2 = fmaf(w2.z, preg[g + 10], acc2);
                    acc2 = fmaf(w2.w, preg[g + 11], acc2);
                    acc3 = fmaf(w3.x, preg[g + 12], acc3);
                    acc3 = fmaf(w3.y, preg[g + 13], acc3);
                    acc3 = fmaf(w3.z, preg[g + 14], acc3);
                    acc3 = fmaf(w3.w, preg[g + 15], acc3);
                }
                float acc = (acc0 + acc1) + (acc2 + acc3);
                atomicAdd(&agg[(size_t)dst * 64 + lane], acc);   // partial; /deg in GRU
            }
        }
    }
}

// ---------------- k_gru: conv (+deg-normalize) + GRU (+ agg re-zero) ----------------
__global__ __launch_bounds__(256) void k_gru(const float* __restrict__ out,
        float* __restrict__ agg, const int* __restrict__ cnt_dst,
        const float* __restrict__ rootW, const float* __restrict__ convb,
        const float* __restrict__ Wih, const float* __restrict__ Whh,
        const float* __restrict__ bih, const float* __restrict__ bhh,
        float* __restrict__ outn) {
    __shared__ float sh[4][64], sc[4][64];
    int t = threadIdx.x, w = t >> 6, j = t & 63;
    int n = blockIdx.x * 4 + w;
    float hj = out[(size_t)n * 64 + j];
    sh[w][j] = hj;
    int dg = cnt_dst[n];
    float invd = 1.0f / (float)(dg > 0 ? dg : 1);
    float av = agg[(size_t)n * 64 + j];
    agg[(size_t)n * 64 + j] = 0.f;          // pre-zero for next layer's atomics
    __syncthreads();
    float s = av * invd + convb[j];
    #pragma unroll 8
    for (int k = 0; k < 64; ++k) s = fmaf(sh[w][k], rootW[k * 64 + j], s);
    float conv = fmaxf(s, 0.f);
    sc[w][j] = conv;
    __syncthreads();
    float gir = bih[j], giz = bih[64 + j], gin = bih[128 + j];
    float ghr = bhh[j], ghz = bhh[64 + j], ghn = bhh[128 + j];
    #pragma unroll 4
    for (int k = 0; k < 64; ++k) {
        float c = sc[w][k], h = sh[w][k];
        gir = fmaf(c, Wih[k * 192 + j], gir);
        giz = fmaf(c, Wih[k * 192 + 64 + j], giz);
        gin = fmaf(c, Wih[k * 192 + 128 + j], gin);
        ghr = fmaf(h, Whh[k * 192 + j], ghr);
        ghz = fmaf(h, Whh[k * 192 + 64 + j], ghz);
        ghn = fmaf(h, Whh[k * 192 + 128 + j], ghn);
    }
    float r = sigf(gir + ghr);
    float z = sigf(giz + ghz);
    float nn = tanhf(gin + r * ghn);
    outn[(size_t)n * 64 + j] = (1.f - z) * nn + z * hj;
}

// ---------------- Set2Set (3 steps) + post-MLP: burst-latency version ---------------
__global__ __launch_bounds__(256, 1) void k_s2s_post(const float* __restrict__ out,
        const int* __restrict__ bstart, const int* __restrict__ bend,
        const float* __restrict__ WihT, const float* __restrict__ WhhT,
        const float* __restrict__ bih, const float* __restrict__ bhh,
        const float* __restrict__ pW0, const float* __restrict__ pb0,
        const float* __restrict__ pW1, const float* __restrict__ pb1,
        const float* __restrict__ pW2, const float* __restrict__ pb2,
        const float* __restrict__ pW3, const float* __restrict__ pb3,
        float* __restrict__ y) {
    __shared__ float cacheT[64 * 193];     // transposed node tile (49.4 KB)
    __shared__ float wpost[16448];         // pW0|pW1|pW2|pW3 (64.3 KB)
    __shared__ float qs[128];              // [0:64]=q(hh), [64:128]=r_read
    __shared__ float hh_l[64];
    __shared__ float gates_l[256];
    __shared__ float ebuf[1024];
    __shared__ float redw[4], redw2[4];
    __shared__ float redbuf[4][64];
    __shared__ float tmp64[64];
    int t = threadIdx.x, wave = t >> 6, lane = t & 63;
    int b = blockIdx.x;
    int s0 = bstart[b], e0 = bend[b];
    int cnt = e0 - s0;
    if (cnt < 0) cnt = 0;
    if (cnt > 1024) cnt = 1024;
    int ccnt = cnt < 192 ? cnt : 192;
    // ---- burst 1: node tile (<=192 rows -> <=3072 float4, 12 guarded/thread) ----
    int nf4 = ccnt * 16;
    const float4* out4 = (const float4*)(out + (size_t)s0 * 64);
    float4 stg[12];
    #pragma unroll
    for (int i = 0; i < 12; ++i) {
        int v = t + i * 256;
        if (v < nf4) stg[i] = out4[v];
    }
    #pragma unroll
    for (int i = 0; i < 12; ++i) {
        int v = t + i * 256;
        if (v < nf4) {
            int row = v >> 4, dq = v & 15;
            cacheT[(dq * 4 + 0) * 193 + row] = stg[i].x;
            cacheT[(dq * 4 + 1) * 193 + row] = stg[i].y;
            cacheT[(dq * 4 + 2) * 193 + row] = stg[i].z;
            cacheT[(dq * 4 + 3) * 193 + row] = stg[i].w;
        }
    }
    // ---- burst 2: post-MLP weights -> LDS (4112 float4 total) ----
    {
        float4* wp4 = (float4*)wpost;
        #pragma unroll
        for (int i = 0; i < 8; ++i) { int v = t + i * 256; wp4[v] = ((const float4*)pW0)[v]; }
        #pragma unroll
        for (int i = 0; i < 4; ++i) { int v = t + i * 256; wp4[2048 + v] = ((const float4*)pW1)[v]; }
        #pragma unroll
        for (int i = 0; i < 4; ++i) { int v = t + i * 256; wp4[3072 + v] = ((const float4*)pW2)[v]; }
        if (t < 16) wp4[4096 + t] = ((const float4*)pW3)[t];
    }
    const float4* wihT4 = (const float4*)(WihT + (size_t)t * 128);
    const float4* whhT4 = (const float4*)(WhhT + (size_t)t * 64);
    float bsum = bih[t] + bhh[t];
    float ccr = 0.f;                       // cc for dim t (threads t<64 only)
    if (t < 128) qs[t] = 0.f;
    if (t < 64) hh_l[t] = 0.f;
    __syncthreads();
    const float4* qs4 = (const float4*)qs;
    const float4* hh4 = (const float4*)hh_l;
    for (int step = 0; step < 3; ++step) {
        float g0 = bsum, g1 = 0.f, g2 = 0.f, g3 = 0.f;
        #pragma unroll
        for (int jq = 0; jq < 32; ++jq) {
            float4 w = wihT4[jq];
            float4 v = qs4[jq];
            g0 = fmaf(v.x, w.x, g0);
            g1 = fmaf(v.y, w.y, g1);
            g2 = fmaf(v.z, w.z, g2);
            g3 = fmaf(v.w, w.w, g3);
        }
        #pragma unroll
        for (int jq = 0; jq < 16; ++jq) {
            float4 w = whhT4[jq];
            float4 v = hh4[jq];
            g0 = fmaf(v.x, w.x, g0);
            g1 = fmaf(v.y, w.y, g1);
            g2 = fmaf(v.z, w.z, g2);
            g3 = fmaf(v.w, w.w, g3);
        }
        gates_l[t] = (g0 + g1) + (g2 + g3);
        __syncthreads();                                     // B1: gates ready
        if (t < 64) {
            float cn = sigf(gates_l[64 + t]) * ccr
                     + sigf(gates_l[t]) * tanhf(gates_l[128 + t]);
            ccr = cn;
            hh_l[t] = sigf(gates_l[192 + t]) * tanhf(cn);
        }
        __syncthreads();                                     // B2: hh ready
        for (int idx = t; idx < cnt; idx += 256) {
            float s0a = 0.f, s1a = 0.f, s2a = 0.f, s3a = 0.f;
            if (idx < 192) {
                #pragma unroll
                for (int dq = 0; dq < 16; ++dq) {
                    float4 h = hh4[dq];
                    s0a = fmaf(cacheT[(dq * 4 + 0) * 193 + idx], h.x, s0a);
                    s1a = fmaf(cacheT[(dq * 4 + 1) * 193 + idx], h.y, s1a);
                    s2a = fmaf(cacheT[(dq * 4 + 2) * 193 + idx], h.z, s2a);
                    s3a = fmaf(cacheT[(dq * 4 + 3) * 193 + idx], h.w, s3a);
                }
            } else {
                const float* row = out + (size_t)(s0 + idx) * 64;
                #pragma unroll
                for (int dq = 0; dq < 16; ++dq) {
                    float4 h = hh4[dq];
                    s0a = fmaf(row[dq * 4 + 0], h.x, s0a);
                    s1a = fmaf(row[dq * 4 + 1], h.y, s1a);
                    s2a = fmaf(row[dq * 4 + 2], h.z, s2a);
                    s3a = fmaf(row[dq * 4 + 3], h.w, s3a);
                }
            }
            ebuf[idx] = (s0a + s1a) + (s2a + s3a);
        }
        __syncthreads();                                     // B3: e ready
        float lm = -3.0e38f;
        for (int idx = t; idx < cnt; idx += 256) lm = fmaxf(lm, ebuf[idx]);
        #pragma unroll
        for (int off = 32; off > 0; off >>= 1) lm = fmaxf(lm, __shfl_xor(lm, off, 64));
        if (lane == 0) redw[wave] = lm;
        __syncthreads();                                     // B4: wave maxes
        float m = fmaxf(fmaxf(redw[0], redw[1]), fmaxf(redw[2], redw[3]));
        float ls = 0.f;
        for (int idx = t; idx < cnt; idx += 256) {
            float a = __expf(ebuf[idx] - m);
            ebuf[idx] = a;
            ls += a;
        }
        #pragma unroll
        for (int off = 32; off > 0; off >>= 1) ls += __shfl_xor(ls, off, 64);
        if (lane == 0) redw2[wave] = ls;
        __syncthreads();                                     // B5: a's + wave sums
        float ssum = (redw2[0] + redw2[1]) + (redw2[2] + redw2[3]);
        float inv = (cnt > 0) ? 1.f / ssum : 0.f;
        float r0 = 0.f;
        for (int row = wave; row < ccnt; row += 4)
            r0 = fmaf(ebuf[row], cacheT[lane * 193 + row], r0);
        for (int row = 192 + wave; row < cnt; row += 4)
            r0 = fmaf(ebuf[row], out[(size_t)(s0 + row) * 64 + lane], r0);
        redbuf[wave][lane] = r0;
        __syncthreads();                                     // B6: wave partials
        if (t < 64) {
            float s = ((redbuf[0][t] + redbuf[1][t]) + (redbuf[2][t] + redbuf[3][t]));
            qs[64 + t] = s * inv;
            qs[t] = hh_l[t];
        }
        __syncthreads();                                     // B7: qs ready
    }
    if (t < 64) {
        float s = pb0[t];
        #pragma unroll 4
        for (int k = 0; k < 128; ++k) s = fmaf(qs[k], wpost[k * 64 + t], s);
        tmp64[t] = fmaxf(s, 0.f);
    }
    __syncthreads();
    float h1v = 0.f;
    if (t < 64) {
        float s = pb1[t];
        #pragma unroll 4
        for (int k = 0; k < 64; ++k) s = fmaf(tmp64[k], wpost[8192 + k * 64 + t], s);
        h1v = fmaxf(s, 0.f);
    }
    __syncthreads();
    if (t < 64) tmp64[t] = h1v;
    __syncthreads();
    if (t < 64) {
        float s = pb2[t];
        #pragma unroll 4
        for (int k = 0; k < 64; ++k) s = fmaf(tmp64[k], wpost[12288 + k * 64 + t], s);
        gates_l[t] = fmaxf(s, 0.f) * wpost[16384 + t];
    }
    __syncthreads();
    if (t == 0) {
        float yy = pb3[0];
        for (int k = 0; k < 64; ++k) yy += gates_l[k];
        y[b] = yy;
    }
}

// ---------------- host ----------------

extern "C" void kernel_launch(void* const* d_in, const int* in_sizes, int n_in,
                              void* d_out, int out_size, void* d_ws, size_t ws_size,
                              hipStream_t stream) {
    const float* x         = (const float*)d_in[0];
    const float* edge_attr = (const float*)d_in[1];
    const int*   edge_idx  = (const int*)d_in[2];
    const int*   batch_map = (const int*)d_in[3];
    const float* pre_W0 = (const float*)d_in[4];
    const float* pre_b0 = (const float*)d_in[5];
    const float* pre_W1 = (const float*)d_in[6];
    const float* pre_b1 = (const float*)d_in[7];
    const float* pre_W2 = (const float*)d_in[8];
    const float* pre_b2 = (const float*)d_in[9];
    const float* enn_W1 = (const float*)d_in[10];
    const float* enn_b1 = (const float*)d_in[11];
    const float* enn_W2 = (const float*)d_in[12];
    const float* enn_b2 = (const float*)d_in[13];
    const float* root_W = (const float*)d_in[14];
    const float* conv_b = (const float*)d_in[15];
    const float* gru_Wih = (const float*)d_in[16];
    const float* gru_Whh = (const float*)d_in[17];
    const float* gru_bih = (const float*)d_in[18];
    const float* gru_bhh = (const float*)d_in[19];
    const float* s2s_Wih = (const float*)d_in[20];
    const float* s2s_Whh = (const float*)d_in[21];
    const float* s2s_bih = (const float*)d_in[22];
    const float* s2s_bhh = (const float*)d_in[23];
    const float* post_W0 = (const float*)d_in[24];
    const float* post_b0 = (const float*)d_in[25];
    const float* post_W1 = (const float*)d_in[26];
    const float* post_b1 = (const float*)d_in[27];
    const float* post_W2 = (const float*)d_in[28];
    const float* post_b2 = (const float*)d_in[29];
    const float* post_W3 = (const float*)d_in[30];
    const float* post_b3 = (const float*)d_in[31];
    float* yout = (float*)d_out;

    char* wp = (char*)d_ws;
    auto take = [&](size_t bytes) -> char* {
        char* r = wp;
        wp += (bytes + 255) & ~(size_t)255;
        return r;
    };
    float* outA = (float*)take((size_t)NN * 64 * 4);
    float* outB = (float*)take((size_t)NN * 64 * 4);
    float* agg  = (float*)take((size_t)NN * 64 * 4);
    __hip_bfloat16* W2F = (__hip_bfloat16*)take((size_t)3 * 64 * 4096 * 2);
    int* cnt_src  = (int*)take((size_t)NN * 4);
    int* cnt_dst  = (int*)take((size_t)NN * 4);
    int* csr_dst  = (int*)take((size_t)NN * BKT * 4);
    float* csr_ea = (float*)take((size_t)NN * BKT * 4);
    int* bstart   = (int*)take((size_t)NB * 4);
    int* bend     = (int*)take((size_t)NB * 4);
    float* WihT   = (float*)take((size_t)256 * 128 * 4);
    float* WhhT   = (float*)take((size_t)256 * 64 * 4);

    k_setup<<<1248, 256, 0, stream>>>(x, pre_W0, pre_b0, pre_W1, pre_b1, pre_W2, pre_b2,
                                      enn_W2, W2F, outA, agg, cnt_src, cnt_dst,
                                      bstart, bend);
    k_bucket<<<160, 256, 0, stream>>>(edge_idx, edge_attr, batch_map,
                                      s2s_Wih, s2s_Whh, WihT, WhhT,
                                      cnt_src, cnt_dst, csr_dst, csr_ea, bstart, bend);

    float* cur = outA;
    float* nxt = outB;
    for (int l = 0; l < 3; ++l) {
        k_fused<<<NN / 8 * 2, 256, 0, stream>>>(cur, W2F + (size_t)l * 64 * 4096,
                                                enn_b2 + (size_t)l * 4096,
                                                enn_W1 + l * 64, enn_b1 + l * 64,
                                                cnt_src, csr_dst, csr_ea, agg);
        k_gru<<<NN / 4, 256, 0, stream>>>(cur, agg, cnt_dst, root_W + l * 4096,
                                          conv_b + l * 64, gru_Wih + l * 64 * 192,
                                          gru_Whh + l * 64 * 192, gru_bih + l * 192,
                                          gru_bhh + l * 192, nxt);
        float* tmp = cur; cur = nxt; nxt = tmp;
    }
    k_s2s_post<<<NB, 256, 0, stream>>>(cur, bstart, bend, WihT, WhhT, s2s_bih,
                                       s2s_bhh, post_W0, post_b0, post_W1, post_b1,
                                       post_W2, post_b2, post_W3, post_b3, yout);
}

// Round 10
// 311.928 us; speedup vs baseline: 3.0078x; 1.0567x over previous
//
#include <hip/hip_runtime.h>
#include <hip/hip_bf16.h>
#include <string.h>

#define NN   4096
#define NE   32768
#define NB   32
#define BKT  64   // per-src edge bucket capacity (deg ~ Poisson(8); P(>64) ~ 1e-30)
#define MSG_CHUNK 8

typedef __attribute__((ext_vector_type(8))) short short8;
typedef __attribute__((ext_vector_type(4))) float f4;

__device__ __forceinline__ float sigf(float x) { return 1.0f / (1.0f + __expf(-x)); }
__device__ __forceinline__ short f2bf(float f) {
    __hip_bfloat16 h = __float2bfloat16(f);
    short s;
    memcpy(&s, &h, sizeof(short));
    return s;
}

// ---------------- k_prep: W2F repack | edge bucket | S2S transpose | pre-MLP -------
// All four block families independent (counters pre-zeroed by hipMemsetAsync):
//   blocks    0..191: enn_W2 -> W2F fragment-packed bf16 (MFMA-ready)
//   blocks 192..319: edge bucket CSR fill (atomics on memset-zeroed counters)
//   blocks 320..351: WihT/WhhT transpose for k_s2s_post
//   blocks 352..1375: pre-MLP (4 nodes per block) + agg zero
__global__ __launch_bounds__(256) void k_prep(const float* __restrict__ x,
        const float* __restrict__ W0, const float* __restrict__ b0,
        const float* __restrict__ W1, const float* __restrict__ b1,
        const float* __restrict__ W2, const float* __restrict__ b2,
        const float* __restrict__ enn_W2, __hip_bfloat16* __restrict__ W2F,
        const int* __restrict__ eidx, const float* __restrict__ ea,
        const float* __restrict__ Wih, const float* __restrict__ Whh,
        float* __restrict__ WihT, float* __restrict__ WhhT,
        float* __restrict__ out, float* __restrict__ agg,
        int* cnt_src, int* cnt_dst, int* csr_dst, float* csr_ea) {
    int bid = blockIdx.x, t = threadIdx.x;
    if (bid < 192) {
        __shared__ __hip_bfloat16 tile[4096];
        size_t base = (size_t)bid * 4096;
        for (int i = t; i < 4096; i += 256) {
            int k = i >> 6, o = i & 63;
            int pos = ((o >> 4) << 10) | ((k >> 5) << 9) | (((k >> 3) & 3) << 7)
                    | ((o & 15) << 3) | (k & 7);
            tile[pos] = __float2bfloat16(enn_W2[base + i]);
        }
        __syncthreads();
        for (int i = t; i < 4096; i += 256) W2F[base + i] = tile[i];
    } else if (bid < 320) {
        int e = (bid - 192) * 256 + t;                 // 128*256 == NE exactly
        int s = eidx[e];
        int d = eidx[NE + e];
        int slot = atomicAdd(&cnt_src[s], 1);
        if (slot < BKT) {
            csr_dst[s * BKT + slot] = d;
            csr_ea[s * BKT + slot] = ea[e];
        }
        atomicAdd(&cnt_dst[d], 1);
    } else if (bid < 352) {
        int c0 = (bid - 320) * 8;
        for (int i = t; i < 1024; i += 256) {
            int c = c0 + (i >> 7), j = i & 127;
            WihT[(size_t)c * 128 + j] = Wih[(size_t)j * 256 + c];
        }
        for (int i = t; i < 512; i += 256) {
            int c = c0 + (i >> 6), j = i & 63;
            WhhT[(size_t)c * 64 + j] = Whh[(size_t)j * 256 + c];
        }
    } else {
        __shared__ float xr[4][128], ha[4][64], hb[4][64];
        int w = t >> 6, j = t & 63;
        int n = (bid - 352) * 4 + w;
        xr[w][j] = x[(size_t)n * 128 + j];
        xr[w][64 + j] = x[(size_t)n * 128 + 64 + j];
        agg[(size_t)n * 64 + j] = 0.f;
        float s = b0[j];
        #pragma unroll 8
        for (int k = 0; k < 128; ++k) s = fmaf(xr[w][k], W0[k * 64 + j], s);
        ha[w][j] = fmaxf(s, 0.f);
        s = b1[j];
        #pragma unroll 8
        for (int k = 0; k < 64; ++k) s = fmaf(ha[w][k], W1[k * 64 + j], s);
        hb[w][j] = fmaxf(s, 0.f);
        s = b2[j];
        #pragma unroll 8
        for (int k = 0; k < 64; ++k) s = fmaf(hb[w][k], W2[k * 64 + j], s);
        out[(size_t)n * 64 + j] = fmaxf(s, 0.f);
    }
}

// ---------------- k_fused: half-g P-tile MFMA in LDS + message scatter --------------
// Block = (8-node tile) x (g-chunk of 32). ntile = bid>>1, gc = bid&1. Grid 1024.
// LDS 38.4 KB -> 4 blocks/CU (16 waves/CU); atomics 2x/edge (partial g-sums).
__global__ __launch_bounds__(256, 4) void k_fused(const float* __restrict__ out,
        const __hip_bfloat16* __restrict__ W2F_l, const float* __restrict__ b2l,
        const float* __restrict__ W1l, const float* __restrict__ b1l,
        const int* __restrict__ cnt_src, const int* __restrict__ csr_dst,
        const float* __restrict__ csr_ea, float* __restrict__ agg) {
    __shared__ __hip_bfloat16 Pt[8 * 2048];           // 32 KB swizzled half-g P tile
    __shared__ float outs[8][68];                     // fp32 node tile (padded)
    __shared__ float wlds[4][MSG_CHUNK][32];          // 4 KB We1 buffers (wave-private)
    int t = threadIdx.x, wave = t >> 6, lane = t & 63;
    int laneM = lane & 15, quad = lane >> 4;
    int ntile = blockIdx.x >> 1, gc = blockIdx.x & 1;
    int n0 = ntile * 8;
    for (int i = t; i < 512; i += 256) outs[i >> 6][i & 63] = out[(size_t)n0 * 64 + i];
    __syncthreads();
    // A fragments (rows = 8 nodes, rows 8..15 duplicated; K = 64)
    short8 a0, a1;
    {
        const float* ar = &outs[laneM & 7][quad * 8];
        #pragma unroll
        for (int j = 0; j < 8; ++j) a0[j] = f2bf(ar[j]);
        const float* ar2 = &outs[laneM & 7][32 + quad * 8];
        #pragma unroll
        for (int j = 0; j < 8; ++j) a1[j] = f2bf(ar2[j]);
    }
    // BT (fp32, same summation order as proven); only gc==0 contributes it
    float btr[2] = {0.f, 0.f};
    if (gc == 0) {
        for (int k = 0; k < 64; ++k) {
            float bv = b2l[k * 64 + lane];
            #pragma unroll
            for (int u = 0; u < 2; ++u) btr[u] = fmaf(outs[wave * 2 + u][k], bv, btr[u]);
        }
    }
    // Phase 1: wave w owns gl in [8w, 8w+8) (octet c = wave), 4 adjacent pairs
    #pragma unroll
    for (int gp = 0; gp < 4; ++gp) {
        int glA = wave * 8 + gp * 2;                   // even local g
        int gA = gc * 32 + glA;
        const __hip_bfloat16* BgA = W2F_l + (size_t)gA * 4096;
        const __hip_bfloat16* BgB = BgA + 4096;
        int c = wave;                                  // glA>>3
        int p = gp;                                    // (glA>>1)&3
        char* wb = (char*)Pt + (quad << 14) + (c << 10) + (laneM << 4)
                 + (((p ^ quad) & 3) << 2);
        #pragma unroll
        for (int sub = 0; sub < 4; ++sub) {
            short8 bA0 = *(const short8*)(BgA + sub * 1024 + lane * 8);
            short8 bA1 = *(const short8*)(BgA + sub * 1024 + 512 + lane * 8);
            short8 bB0 = *(const short8*)(BgB + sub * 1024 + lane * 8);
            short8 bB1 = *(const short8*)(BgB + sub * 1024 + 512 + lane * 8);
            f4 accA = {0.f, 0.f, 0.f, 0.f}, accB = {0.f, 0.f, 0.f, 0.f};
            accA = __builtin_amdgcn_mfma_f32_16x16x32_bf16(a0, bA0, accA, 0, 0, 0);
            accA = __builtin_amdgcn_mfma_f32_16x16x32_bf16(a1, bA1, accA, 0, 0, 0);
            accB = __builtin_amdgcn_mfma_f32_16x16x32_bf16(a0, bB0, accB, 0, 0, 0);
            accB = __builtin_amdgcn_mfma_f32_16x16x32_bf16(a1, bB1, accB, 0, 0, 0);
            if (quad < 2) {                            // nodes = quad*4+r in 0..7
                char* wbs = wb + (sub << 8);           // o += 16 -> 256 B
                #pragma unroll
                for (int r = 0; r < 4; ++r) {
                    unsigned pk = (unsigned)(unsigned short)f2bf(accA[r])
                                | ((unsigned)(unsigned short)f2bf(accB[r]) << 16);
                    *(unsigned*)(wbs + (r << 12)) = pk;    // node stride 4096 B
                }
            }
        }
    }
    __syncthreads();
    // Phase 2: partial-g message scatter, 2 srcs per wave, one atomic per (edge, gc)
    float w1v = (lane < 32) ? W1l[gc * 32 + lane] : 0.f;
    float b1v = (lane < 32) ? b1l[gc * 32 + lane] : 0.f;
    for (int u = 0; u < 2; ++u) {
        int nloc = wave * 2 + u;
        int n = n0 + nloc;
        int deg = cnt_src[n];
        if (deg > BKT) deg = BKT;
        if (deg <= 0) continue;
        int wq = nloc >> 2;                            // writer quad (0 or 1)
        float preg[32];                                // P[n, gl 0..31, o=lane]
        const char* Pn = (const char*)Pt + (nloc << 12);
        #pragma unroll
        for (int c2 = 0; c2 < 4; ++c2) {
            uint4 vv = *(const uint4*)(Pn + (c2 << 10) + (lane << 4));
            unsigned d0 = vv.x, d1 = vv.y, d2 = vv.z, d3 = vv.w;
            if (wq & 1) { unsigned tt = d0; d0 = d1; d1 = tt; tt = d2; d2 = d3; d3 = tt; }
            union { unsigned u2; float f; } cv;
            cv.u2 = d0 << 16;          preg[c2 * 8 + 0] = cv.f;
            cv.u2 = d0 & 0xFFFF0000u;  preg[c2 * 8 + 1] = cv.f;
            cv.u2 = d1 << 16;          preg[c2 * 8 + 2] = cv.f;
            cv.u2 = d1 & 0xFFFF0000u;  preg[c2 * 8 + 3] = cv.f;
            cv.u2 = d2 << 16;          preg[c2 * 8 + 4] = cv.f;
            cv.u2 = d2 & 0xFFFF0000u;  preg[c2 * 8 + 5] = cv.f;
            cv.u2 = d3 << 16;          preg[c2 * 8 + 6] = cv.f;
            cv.u2 = d3 & 0xFFFF0000u;  preg[c2 * 8 + 7] = cv.f;
        }
        float bt = btr[u];                             // 0 unless gc==0
        const int* bdst = csr_dst + n * BKT;
        const float* bea = csr_ea + n * BKT;
        for (int c0 = 0; c0 < deg; c0 += MSG_CHUNK) {
            int cc = deg - c0;
            if (cc > MSG_CHUNK) cc = MSG_CHUNK;
            int dl = 0; float el = 0.f;
            if (lane < cc) { dl = bdst[c0 + lane]; el = bea[c0 + lane]; }
            for (int si = 0; si < cc; ++si) {
                float eav = __shfl(el, si, 64);
                if (lane < 32)
                    wlds[wave][si][lane] = fmaxf(fmaf(eav, w1v, b1v), 0.f);  // lane = gl
            }
            for (int i = 0; i < cc; ++i) {
                int dst = __shfl(dl, i, 64);
                const float* wr = wlds[wave][i];
                float acc0 = bt, acc1 = 0.f, acc2 = 0.f, acc3 = 0.f;
                #pragma unroll
                for (int g = 0; g < 32; g += 16) {
                    float4 w0 = *(const float4*)(wr + g);
                    float4 w1 = *(const float4*)(wr + g + 4);
                    float4 w2 = *(const float4*)(wr + g + 8);
                    float4 w3 = *(const float4*)(wr + g + 12);
                    acc0 = fmaf(w0.x, preg[g], acc0);
                    acc0 = fmaf(w0.y, preg[g + 1], acc0);
                    acc0 = fmaf(w0.z, preg[g + 2], acc0);
                    acc0 = fmaf(w0.w, preg[g + 3], acc0);
                    acc1 = fmaf(w1.x, preg[g + 4], acc1);
                    acc1 = fmaf(w1.y, preg[g + 5], acc1);
                    acc1 = fmaf(w1.z, preg[g + 6], acc1);
                    acc1 = fmaf(w1.w, preg[g + 7], acc1);
                    acc2 = fmaf(w2.x, preg[g + 8], acc2);
                    acc2 = fmaf(w2.y, preg[g + 9], acc2);
                    acc2 = fmaf(w2.z, preg[g + 10], acc2);
                    acc2 = fmaf(w2.w, preg[g + 11], acc2);
                    acc3 = fmaf(w3.x, preg[g + 12], acc3);
                    acc3 = fmaf(w3.y, preg[g + 13], acc3);
                    acc3 = fmaf(w3.z, preg[g + 14], acc3);
                    acc3 = fmaf(w3.w, preg[g + 15], acc3);
                }
                float acc = (acc0 + acc1) + (acc2 + acc3);
                atomicAdd(&agg[(size_t)dst * 64 + lane], acc);   // partial; /deg in GRU
            }
        }
    }
}

// ---------------- k_gru: conv (+deg-normalize) + GRU (+ agg re-zero) ----------------
__global__ __launch_bounds__(256) void k_gru(const float* __restrict__ out,
        float* __restrict__ agg, const int* __restrict__ cnt_dst,
        const float* __restrict__ rootW, const float* __restrict__ convb,
        const float* __restrict__ Wih, const float* __restrict__ Whh,
        const float* __restrict__ bih, const float* __restrict__ bhh,
        float* __restrict__ outn) {
    __shared__ float sh[4][64], sc[4][64];
    int t = threadIdx.x, w = t >> 6, j = t & 63;
    int n = blockIdx.x * 4 + w;
    float hj = out[(size_t)n * 64 + j];
    sh[w][j] = hj;
    int dg = cnt_dst[n];
    float invd = 1.0f / (float)(dg > 0 ? dg : 1);
    float av = agg[(size_t)n * 64 + j];
    agg[(size_t)n * 64 + j] = 0.f;          // pre-zero for next layer's atomics
    __syncthreads();
    float s = av * invd + convb[j];
    #pragma unroll 8
    for (int k = 0; k < 64; ++k) s = fmaf(sh[w][k], rootW[k * 64 + j], s);
    float conv = fmaxf(s, 0.f);
    sc[w][j] = conv;
    __syncthreads();
    float gir = bih[j], giz = bih[64 + j], gin = bih[128 + j];
    float ghr = bhh[j], ghz = bhh[64 + j], ghn = bhh[128 + j];
    #pragma unroll 4
    for (int k = 0; k < 64; ++k) {
        float c = sc[w][k], h = sh[w][k];
        gir = fmaf(c, Wih[k * 192 + j], gir);
        giz = fmaf(c, Wih[k * 192 + 64 + j], giz);
        gin = fmaf(c, Wih[k * 192 + 128 + j], gin);
        ghr = fmaf(h, Whh[k * 192 + j], ghr);
        ghz = fmaf(h, Whh[k * 192 + 64 + j], ghz);
        ghn = fmaf(h, Whh[k * 192 + 128 + j], ghn);
    }
    float r = sigf(gir + ghr);
    float z = sigf(giz + ghz);
    float nn = tanhf(gin + r * ghn);
    outn[(size_t)n * 64 + j] = (1.f - z) * nn + z * hj;
}

// ---------------- Set2Set (3 steps) + post-MLP: burst-latency version ---------------
// Batch range via binary search over sorted batch_map (replaces bstart/bend arrays
// and their init/atomic pass). Otherwise identical to the proven R6 kernel.
__global__ __launch_bounds__(256, 1) void k_s2s_post(const float* __restrict__ out,
        const int* __restrict__ bm,
        const float* __restrict__ WihT, const float* __restrict__ WhhT,
        const float* __restrict__ bih, const float* __restrict__ bhh,
        const float* __restrict__ pW0, const float* __restrict__ pb0,
        const float* __restrict__ pW1, const float* __restrict__ pb1,
        const float* __restrict__ pW2, const float* __restrict__ pb2,
        const float* __restrict__ pW3, const float* __restrict__ pb3,
        float* __restrict__ y) {
    __shared__ float cacheT[64 * 193];     // transposed node tile (49.4 KB)
    __shared__ float wpost[16448];         // pW0|pW1|pW2|pW3 (64.3 KB)
    __shared__ float qs[128];              // [0:64]=q(hh), [64:128]=r_read
    __shared__ float hh_l[64];
    __shared__ float gates_l[256];
    __shared__ float ebuf[1024];
    __shared__ float redw[4], redw2[4];
    __shared__ float redbuf[4][64];
    __shared__ float tmp64[64];
    int t = threadIdx.x, wave = t >> 6, lane = t & 63;
    int b = blockIdx.x;
    // lower_bound(bm, b) and lower_bound(bm, b+1) -- bm sorted, broadcast loads
    int s0, e0;
    {
        int lo = 0, hi = NN;
        while (lo < hi) { int mid = (lo + hi) >> 1; if (bm[mid] < b) lo = mid + 1; else hi = mid; }
        s0 = lo;
        hi = NN;
        while (lo < hi) { int mid = (lo + hi) >> 1; if (bm[mid] < b + 1) lo = mid + 1; else hi = mid; }
        e0 = lo;
    }
    int cnt = e0 - s0;
    if (cnt < 0) cnt = 0;
    if (cnt > 1024) cnt = 1024;
    int ccnt = cnt < 192 ? cnt : 192;
    // ---- burst 1: node tile (<=192 rows -> <=3072 float4, 12 guarded/thread) ----
    int nf4 = ccnt * 16;
    const float4* out4 = (const float4*)(out + (size_t)s0 * 64);
    float4 stg[12];
    #pragma unroll
    for (int i = 0; i < 12; ++i) {
        int v = t + i * 256;
        if (v < nf4) stg[i] = out4[v];
    }
    #pragma unroll
    for (int i = 0; i < 12; ++i) {
        int v = t + i * 256;
        if (v < nf4) {
            int row = v >> 4, dq = v & 15;
            cacheT[(dq * 4 + 0) * 193 + row] = stg[i].x;
            cacheT[(dq * 4 + 1) * 193 + row] = stg[i].y;
            cacheT[(dq * 4 + 2) * 193 + row] = stg[i].z;
            cacheT[(dq * 4 + 3) * 193 + row] = stg[i].w;
        }
    }
    // ---- burst 2: post-MLP weights -> LDS (4112 float4 total) ----
    {
        float4* wp4 = (float4*)wpost;
        #pragma unroll
        for (int i = 0; i < 8; ++i) { int v = t + i * 256; wp4[v] = ((const float4*)pW0)[v]; }
        #pragma unroll
        for (int i = 0; i < 4; ++i) { int v = t + i * 256; wp4[2048 + v] = ((const float4*)pW1)[v]; }
        #pragma unroll
        for (int i = 0; i < 4; ++i) { int v = t + i * 256; wp4[3072 + v] = ((const float4*)pW2)[v]; }
        if (t < 16) wp4[4096 + t] = ((const float4*)pW3)[t];
    }
    const float4* wihT4 = (const float4*)(WihT + (size_t)t * 128);
    const float4* whhT4 = (const float4*)(WhhT + (size_t)t * 64);
    float bsum = bih[t] + bhh[t];
    float ccr = 0.f;                       // cc for dim t (threads t<64 only)
    if (t < 128) qs[t] = 0.f;
    if (t < 64) hh_l[t] = 0.f;
    __syncthreads();
    const float4* qs4 = (const float4*)qs;
    const float4* hh4 = (const float4*)hh_l;
    for (int step = 0; step < 3; ++step) {
        float g0 = bsum, g1 = 0.f, g2 = 0.f, g3 = 0.f;
        #pragma unroll
        for (int jq = 0; jq < 32; ++jq) {
            float4 w = wihT4[jq];
            float4 v = qs4[jq];
            g0 = fmaf(v.x, w.x, g0);
            g1 = fmaf(v.y, w.y, g1);
            g2 = fmaf(v.z, w.z, g2);
            g3 = fmaf(v.w, w.w, g3);
        }
        #pragma unroll
        for (int jq = 0; jq < 16; ++jq) {
            float4 w = whhT4[jq];
            float4 v = hh4[jq];
            g0 = fmaf(v.x, w.x, g0);
            g1 = fmaf(v.y, w.y, g1);
            g2 = fmaf(v.z, w.z, g2);
            g3 = fmaf(v.w, w.w, g3);
        }
        gates_l[t] = (g0 + g1) + (g2 + g3);
        __syncthreads();                                     // B1: gates ready
        if (t < 64) {
            float cn = sigf(gates_l[64 + t]) * ccr
                     + sigf(gates_l[t]) * tanhf(gates_l[128 + t]);
            ccr = cn;
            hh_l[t] = sigf(gates_l[192 + t]) * tanhf(cn);
        }
        __syncthreads();                                     // B2: hh ready
        for (int idx = t; idx < cnt; idx += 256) {
            float s0a = 0.f, s1a = 0.f, s2a = 0.f, s3a = 0.f;
            if (idx < 192) {
                #pragma unroll
                for (int dq = 0; dq < 16; ++dq) {
                    float4 h = hh4[dq];
                    s0a = fmaf(cacheT[(dq * 4 + 0) * 193 + idx], h.x, s0a);
                    s1a = fmaf(cacheT[(dq * 4 + 1) * 193 + idx], h.y, s1a);
                    s2a = fmaf(cacheT[(dq * 4 + 2) * 193 + idx], h.z, s2a);
                    s3a = fmaf(cacheT[(dq * 4 + 3) * 193 + idx], h.w, s3a);
                }
            } else {
                const float* row = out + (size_t)(s0 + idx) * 64;
                #pragma unroll
                for (int dq = 0; dq < 16; ++dq) {
                    float4 h = hh4[dq];
                    s0a = fmaf(row[dq * 4 + 0], h.x, s0a);
                    s1a = fmaf(row[dq * 4 + 1], h.y, s1a);
                    s2a = fmaf(row[dq * 4 + 2], h.z, s2a);
                    s3a = fmaf(row[dq * 4 + 3], h.w, s3a);
                }
            }
            ebuf[idx] = (s0a + s1a) + (s2a + s3a);
        }
        __syncthreads();                                     // B3: e ready
        float lm = -3.0e38f;
        for (int idx = t; idx < cnt; idx += 256) lm = fmaxf(lm, ebuf[idx]);
        #pragma unroll
        for (int off = 32; off > 0; off >>= 1) lm = fmaxf(lm, __shfl_xor(lm, off, 64));
        if (lane == 0) redw[wave] = lm;
        __syncthreads();                                     // B4: wave maxes
        float m = fmaxf(fmaxf(redw[0], redw[1]), fmaxf(redw[2], redw[3]));
        float ls = 0.f;
        for (int idx = t; idx < cnt; idx += 256) {
            float a = __expf(ebuf[idx] - m);
            ebuf[idx] = a;
            ls += a;
        }
        #pragma unroll
        for (int off = 32; off > 0; off >>= 1) ls += __shfl_xor(ls, off, 64);
        if (lane == 0) redw2[wave] = ls;
        __syncthreads();                                     // B5: a's + wave sums
        float ssum = (redw2[0] + redw2[1]) + (redw2[2] + redw2[3]);
        float inv = (cnt > 0) ? 1.f / ssum : 0.f;
        float r0 = 0.f;
        for (int row = wave; row < ccnt; row += 4)
            r0 = fmaf(ebuf[row], cacheT[lane * 193 + row], r0);
        for (int row = 192 + wave; row < cnt; row += 4)
            r0 = fmaf(ebuf[row], out[(size_t)(s0 + row) * 64 + lane], r0);
        redbuf[wave][lane] = r0;
        __syncthreads();                                     // B6: wave partials
        if (t < 64) {
            float s = ((redbuf[0][t] + redbuf[1][t]) + (redbuf[2][t] + redbuf[3][t]));
            qs[64 + t] = s * inv;
            qs[t] = hh_l[t];
        }
        __syncthreads();                                     // B7: qs ready
    }
    if (t < 64) {
        float s = pb0[t];
        #pragma unroll 4
        for (int k = 0; k < 128; ++k) s = fmaf(qs[k], wpost[k * 64 + t], s);
        tmp64[t] = fmaxf(s, 0.f);
    }
    __syncthreads();
    float h1v = 0.f;
    if (t < 64) {
        float s = pb1[t];
        #pragma unroll 4
        for (int k = 0; k < 64; ++k) s = fmaf(tmp64[k], wpost[8192 + k * 64 + t], s);
        h1v = fmaxf(s, 0.f);
    }
    __syncthreads();
    if (t < 64) tmp64[t] = h1v;
    __syncthreads();
    if (t < 64) {
        float s = pb2[t];
        #pragma unroll 4
        for (int k = 0; k < 64; ++k) s = fmaf(tmp64[k], wpost[12288 + k * 64 + t], s);
        gates_l[t] = fmaxf(s, 0.f) * wpost[16384 + t];
    }
    __syncthreads();
    if (t == 0) {
        float yy = pb3[0];
        for (int k = 0; k < 64; ++k) yy += gates_l[k];
        y[b] = yy;
    }
}

// ---------------- host ----------------

extern "C" void kernel_launch(void* const* d_in, const int* in_sizes, int n_in,
                              void* d_out, int out_size, void* d_ws, size_t ws_size,
                              hipStream_t stream) {
    const float* x         = (const float*)d_in[0];
    const float* edge_attr = (const float*)d_in[1];
    const int*   edge_idx  = (const int*)d_in[2];
    const int*   batch_map = (const int*)d_in[3];
    const float* pre_W0 = (const float*)d_in[4];
    const float* pre_b0 = (const float*)d_in[5];
    const float* pre_W1 = (const float*)d_in[6];
    const float* pre_b1 = (const float*)d_in[7];
    const float* pre_W2 = (const float*)d_in[8];
    const float* pre_b2 = (const float*)d_in[9];
    const float* enn_W1 = (const float*)d_in[10];
    const float* enn_b1 = (const float*)d_in[11];
    const float* enn_W2 = (const float*)d_in[12];
    const float* enn_b2 = (const float*)d_in[13];
    const float* root_W = (const float*)d_in[14];
    const float* conv_b = (const float*)d_in[15];
    const float* gru_Wih = (const float*)d_in[16];
    const float* gru_Whh = (const float*)d_in[17];
    const float* gru_bih = (const float*)d_in[18];
    const float* gru_bhh = (const float*)d_in[19];
    const float* s2s_Wih = (const float*)d_in[20];
    const float* s2s_Whh = (const float*)d_in[21];
    const float* s2s_bih = (const float*)d_in[22];
    const float* s2s_bhh = (const float*)d_in[23];
    const float* post_W0 = (const float*)d_in[24];
    const float* post_b0 = (const float*)d_in[25];
    const float* post_W1 = (const float*)d_in[26];
    const float* post_b1 = (const float*)d_in[27];
    const float* post_W2 = (const float*)d_in[28];
    const float* post_b2 = (const float*)d_in[29];
    const float* post_W3 = (const float*)d_in[30];
    const float* post_b3 = (const float*)d_in[31];
    float* yout = (float*)d_out;

    char* wp = (char*)d_ws;
    auto take = [&](size_t bytes) -> char* {
        char* r = wp;
        wp += (bytes + 255) & ~(size_t)255;
        return r;
    };
    float* outA = (float*)take((size_t)NN * 64 * 4);
    float* outB = (float*)take((size_t)NN * 64 * 4);
    float* agg  = (float*)take((size_t)NN * 64 * 4);
    __hip_bfloat16* W2F = (__hip_bfloat16*)take((size_t)3 * 64 * 4096 * 2);
    int* cnt_src  = (int*)take((size_t)NN * 4);       // contiguous with cnt_dst:
    int* cnt_dst  = (int*)take((size_t)NN * 4);       //   one 32 KB memset covers both
    int* csr_dst  = (int*)take((size_t)NN * BKT * 4);
    float* csr_ea = (float*)take((size_t)NN * BKT * 4);
    float* WihT   = (float*)take((size_t)256 * 128 * 4);
    float* WhhT   = (float*)take((size_t)256 * 64 * 4);

    hipMemsetAsync(cnt_src, 0, (size_t)2 * NN * 4, stream);   // cnt_src + cnt_dst

    k_prep<<<1376, 256, 0, stream>>>(x, pre_W0, pre_b0, pre_W1, pre_b1, pre_W2, pre_b2,
                                     enn_W2, W2F, edge_idx, edge_attr,
                                     s2s_Wih, s2s_Whh, WihT, WhhT,
                                     outA, agg, cnt_src, cnt_dst, csr_dst, csr_ea);

    float* cur = outA;
    float* nxt = outB;
    for (int l = 0; l < 3; ++l) {
        k_fused<<<NN / 8 * 2, 256, 0, stream>>>(cur, W2F + (size_t)l * 64 * 4096,
                                                enn_b2 + (size_t)l * 4096,
                                                enn_W1 + l * 64, enn_b1 + l * 64,
                                                cnt_src, csr_dst, csr_ea, agg);
        k_gru<<<NN / 4, 256, 0, stream>>>(cur, agg, cnt_dst, root_W + l * 4096,
                                          conv_b + l * 64, gru_Wih + l * 64 * 192,
                                          gru_Whh + l * 64 * 192, gru_bih + l * 192,
                                          gru_bhh + l * 192, nxt);
        float* tmp = cur; cur = nxt; nxt = tmp;
    }
    k_s2s_post<<<NB, 256, 0, stream>>>(cur, batch_map, WihT, WhhT, s2s_bih,
                                       s2s_bhh, post_W0, post_b0, post_W1, post_b1,
                                       post_W2, post_b2, post_W3, post_b3, yout);
}